// Round 1
// baseline (671.428 us; speedup 1.0000x reference)
//
#include <hip/hip_runtime.h>
#include <hip/hip_bf16.h>

typedef __attribute__((ext_vector_type(8))) short short8;
typedef __attribute__((ext_vector_type(4))) float f32x4;
typedef __attribute__((ext_vector_type(4))) unsigned short us4;

#define MFMA(a, b, c) __builtin_amdgcn_mfma_f32_16x16x32_bf16((a), (b), (c), 0, 0, 0)

static __device__ inline unsigned short f2b(float f) {
    __hip_bfloat16 h = __float2bfloat16(f);
    return *reinterpret_cast<unsigned short*>(&h);
}

// ---------------- f32 -> bf16 conversion (up to 4 tensors via grid.y) ----------------
__global__ __launch_bounds__(256) void convk(
    const float* __restrict__ a, const float* __restrict__ b,
    const float* __restrict__ c, const float* __restrict__ dd,
    unsigned short* oa, unsigned short* ob, unsigned short* oc, unsigned short* od, int n)
{
    const float* in; unsigned short* out;
    switch (blockIdx.y) {
        case 0: in = a; out = oa; break;
        case 1: in = b; out = ob; break;
        case 2: in = c; out = oc; break;
        default: in = dd; out = od; break;
    }
    int i = (blockIdx.x * 256 + threadIdx.x) * 4;
    if (i >= n) return;
    float4 v = *(const float4*)(in + i);
    us4 o;
    o[0] = f2b(v.x); o[1] = f2b(v.y); o[2] = f2b(v.z); o[3] = f2b(v.w);
    *(us4*)(out + i) = o;
}

// ---------------- bf16 GEMM, C = A * B^T (+bias), templated epilogue ----------------
// A [M,K] bf16 row-major, Bm [N,K] bf16 row-major (i.e. B^T layout).
// EMODE 0: f32 row-major out.  EMODE 1: bf16 out in [B,H,S,dk] layout.
// EMODE 2: bf16 out in [B,H,dk,S] (transposed-head) layout.
template<int EMODE>
__global__ __launch_bounds__(256) void gemm_bt(
    const unsigned short* __restrict__ A,
    const unsigned short* __restrict__ Bm,
    const float* __restrict__ bias,
    float* __restrict__ Cf,
    unsigned short* __restrict__ Cb,
    int M, int N, int K)
{
    __shared__ unsigned short sA[128 * 40];  // stride 40 = 32 + 8 pad
    __shared__ unsigned short sB[128 * 40];
    const int tid = threadIdx.x;
    const int wave = tid >> 6, lane = tid & 63;
    const int wm = (wave >> 1) * 64, wn = (wave & 1) * 64;
    const int bm = blockIdx.x * 128, bn = blockIdx.y * 128;
    const int fr = lane & 15, fg = lane >> 4;

    f32x4 acc[4][4] = {};

    for (int kt = 0; kt < K; kt += 32) {
        __syncthreads();
        #pragma unroll
        for (int i = 0; i < 2; ++i) {
            int idx = tid + i * 256;        // 0..511
            int r = idx >> 2, c = (idx & 3) * 8;
            *(short8*)&sA[r * 40 + c] = *(const short8*)&A[(size_t)(bm + r) * K + kt + c];
            *(short8*)&sB[r * 40 + c] = *(const short8*)&Bm[(size_t)(bn + r) * K + kt + c];
        }
        __syncthreads();
        short8 af[4], bf[4];
        #pragma unroll
        for (int mr = 0; mr < 4; ++mr) af[mr] = *(const short8*)&sA[(wm + mr * 16 + fr) * 40 + fg * 8];
        #pragma unroll
        for (int nr = 0; nr < 4; ++nr) bf[nr] = *(const short8*)&sB[(wn + nr * 16 + fr) * 40 + fg * 8];
        #pragma unroll
        for (int mr = 0; mr < 4; ++mr)
            #pragma unroll
            for (int nr = 0; nr < 4; ++nr)
                acc[mr][nr] = MFMA(af[mr], bf[nr], acc[mr][nr]);
    }

    #pragma unroll
    for (int mr = 0; mr < 4; ++mr)
        #pragma unroll
        for (int nr = 0; nr < 4; ++nr)
            #pragma unroll
            for (int j = 0; j < 4; ++j) {
                int m = bm + wm + mr * 16 + fg * 4 + j;
                int n = bn + wn + nr * 16 + fr;
                float v = acc[mr][nr][j] + bias[n];
                if (EMODE == 0) {
                    Cf[(size_t)m * N + n] = v;
                } else if (EMODE == 1) {
                    int b = m >> 10, s = m & 1023, h = n >> 6, dc = n & 63;
                    Cb[(((size_t)(b * 16 + h)) * 1024 + s) * 64 + dc] = f2b(v);
                } else {
                    int b = m >> 10, s = m & 1023, h = n >> 6, dc = n & 63;
                    Cb[(((size_t)(b * 16 + h)) * 64 + dc) * 1024 + s] = f2b(v);
                }
            }
}

// ---------------- fused forget-attention ----------------
// grid (S/16, B*H), 256 threads. One block: 16 query rows of one head.
__global__ __launch_bounds__(256) void attn_fused(
    const unsigned short* __restrict__ Qh,   // [BH,S,64] bf16
    const unsigned short* __restrict__ Kh,   // [BH,S,64] bf16
    const unsigned short* __restrict__ Vt,   // [BH,64,S] bf16
    const float* __restrict__ gammas,        // [16]
    float* __restrict__ attn_out,            // [BH,S,S] f32
    unsigned short* __restrict__ ctx)        // [B*S,1024] bf16
{
    extern __shared__ char smem[];
    float* s_s = (float*)smem;                                            // [16][1034]
    unsigned short* s_p = (unsigned short*)(smem + 16 * 1034 * 4);        // [16][1032]
    unsigned short* s_q = (unsigned short*)(smem + 16 * 1034 * 4 + 16 * 1032 * 2); // [16][72]
    const int S = 1024;
    const int qb = blockIdx.x, bh = blockIdx.y;
    const int q0 = qb * 16;
    const int tid = threadIdx.x;
    const int wave = tid >> 6, lane = tid & 63, fr = lane & 15, fg = lane >> 4;

    // load Q tile [16][64]
    {
        int rr = tid >> 4, c4 = (tid & 15) * 4;
        *(uint2*)&s_q[rr * 72 + c4] = *(const uint2*)&Qh[((size_t)bh * S + q0 + rr) * 64 + c4];
    }
    __syncthreads();
    const int kmax = q0 + 15;

    // phase 1: scores = QK^T / 8 into LDS (each wave: 256-col strip)
    {
        short8 qf0 = *(const short8*)&s_q[fr * 72 + fg * 8];
        short8 qf1 = *(const short8*)&s_q[fr * 72 + 32 + fg * 8];
        const unsigned short* kbase = &Kh[(size_t)bh * S * 64];
        for (int nf = 0; nf < 16; ++nf) {
            int cb = wave * 256 + nf * 16;
            if (cb > kmax) break;   // wave-uniform causal skip
            const unsigned short* kb = kbase + (size_t)cb * 64;
            short8 kf0 = *(const short8*)&kb[fr * 64 + fg * 8];
            short8 kf1 = *(const short8*)&kb[fr * 64 + 32 + fg * 8];
            f32x4 a = {0.f, 0.f, 0.f, 0.f};
            a = MFMA(qf0, kf0, a);
            a = MFMA(qf1, kf1, a);
            #pragma unroll
            for (int j = 0; j < 4; ++j)
                s_s[(fg * 4 + j) * 1034 + cb + fr] = a[j] * 0.125f;
        }
    }
    __syncthreads();

    // phase 2: per-row softmax -> cumsum -> decay -> second softmax
    {
        const int r = tid >> 4, sub = tid & 15;
        const int qr = q0 + r;
        float* srow = &s_s[r * 1034];
        const int base = sub * 64;
        const float ag = fabsf(gammas[bh & 15]);

        float mx = -1e30f;
        for (int i = 0; i < 64; ++i) { int kk = base + i; if (kk <= qr) mx = fmaxf(mx, srow[kk]); }
        #pragma unroll
        for (int m = 1; m < 16; m <<= 1) mx = fmaxf(mx, __shfl_xor(mx, m, 16));

        float ls = 0.f;
        for (int i = 0; i < 64; ++i) { int kk = base + i; if (kk <= qr) ls += __expf(srow[kk] - mx); }
        float incl = ls;
        #pragma unroll
        for (int dlt = 1; dlt < 16; dlt <<= 1) { float o = __shfl_up(incl, dlt, 16); if (sub >= dlt) incl += o; }
        float T = __shfl(incl, 15, 16);
        float excl = incl - ls;
        float invT = 1.f / T;

        float run = excl, mx2 = -1e30f;
        for (int i = 0; i < 64; ++i) {
            int kk = base + i;
            if (kk <= qr) {
                float s = srow[kk];
                float e = __expf(s - mx);
                run += e;
                float rem = fmaxf(T - run, 0.f) * invT;              // 1 - distcum, clipped
                float dist = sqrtf(rem * (float)(qr - kk));
                float te = __expf(-ag * dist);
                te = fminf(fmaxf(te, 1e-5f), 1e5f);
                float g = s * te;
                srow[kk] = g;
                mx2 = fmaxf(mx2, g);
            }
        }
        #pragma unroll
        for (int m = 1; m < 16; m <<= 1) mx2 = fmaxf(mx2, __shfl_xor(mx2, m, 16));

        float ls2 = 0.f;
        for (int i = 0; i < 64; ++i) {
            int kk = base + i;
            float e2 = (kk <= qr) ? __expf(srow[kk] - mx2) : 0.f;
            srow[kk] = e2;
            ls2 += e2;
        }
        #pragma unroll
        for (int m = 1; m < 16; m <<= 1) ls2 += __shfl_xor(ls2, m, 16);
        float inv2 = 1.f / ls2;

        __syncthreads();   // cross-lane interleaved reads of srow next

        float* arow = attn_out + ((size_t)bh * S + qr) * S;
        unsigned short* prow = &s_p[r * 1032];
        for (int i = 0; i < 64; ++i) {
            int kk = i * 16 + sub;                   // coalesced across lanes
            float a = srow[kk] * inv2;
            arow[kk] = a;
            prow[kk] = f2b(a);
        }
    }
    __syncthreads();

    // phase 3: ctx = attn @ V  (each wave: 16 d-columns)
    {
        const unsigned short* vb = &Vt[(size_t)bh * 64 * S];
        f32x4 acc = {0.f, 0.f, 0.f, 0.f};
        int ktiles = (kmax + 32) >> 5;   // ceil((kmax+1)/32)
        for (int kt = 0; kt < ktiles; ++kt) {
            short8 pa = *(const short8*)&s_p[fr * 1032 + kt * 32 + fg * 8];
            short8 vf = *(const short8*)&vb[(size_t)(wave * 16 + fr) * S + kt * 32 + fg * 8];
            acc = MFMA(pa, vf, acc);
        }
        int b = bh >> 4, h = bh & 15;
        #pragma unroll
        for (int j = 0; j < 4; ++j) {
            int row = fg * 4 + j;
            ctx[((size_t)b * S + q0 + row) * 1024 + h * 64 + wave * 16 + fr] = f2b(acc[j]);
        }
    }
}

extern "C" void kernel_launch(void* const* d_in, const int* in_sizes, int n_in,
                              void* d_out, int out_size, void* d_ws, size_t ws_size,
                              hipStream_t stream) {
    const float* query  = (const float*)d_in[0];
    const float* key    = (const float*)d_in[1];
    const float* value  = (const float*)d_in[2];
    // d_in[3] = mask (causal, structurally known) - unused
    const float* Wq = (const float*)d_in[4];
    const float* bq = (const float*)d_in[5];
    const float* Wk = (const float*)d_in[6];
    const float* bk = (const float*)d_in[7];
    const float* Wv = (const float*)d_in[8];
    const float* bv = (const float*)d_in[9];
    const float* Wo = (const float*)d_in[10];
    const float* bo = (const float*)d_in[11];
    const float* gammas = (const float*)d_in[12];

    const int S = 1024, dmodel = 1024;
    const int M = 4 * S;                 // 4096
    const size_t MD = (size_t)M * dmodel;  // 4,194,304
    const size_t DD = (size_t)dmodel * dmodel;

    char* ws = (char*)d_ws;
    unsigned short* xq  = (unsigned short*)ws;            ws += MD * 2;
    unsigned short* xk  = (unsigned short*)ws;            ws += MD * 2;
    unsigned short* xv  = (unsigned short*)ws;            ws += MD * 2;
    unsigned short* wqb = (unsigned short*)ws;            ws += DD * 2;
    unsigned short* wkb = (unsigned short*)ws;            ws += DD * 2;
    unsigned short* wvb = (unsigned short*)ws;            ws += DD * 2;
    unsigned short* wob = (unsigned short*)ws;            ws += DD * 2;
    unsigned short* qh  = (unsigned short*)ws;            ws += MD * 2;
    unsigned short* kh  = (unsigned short*)ws;            ws += MD * 2;
    unsigned short* vt  = (unsigned short*)ws;            ws += MD * 2;
    unsigned short* ctx = (unsigned short*)ws;            ws += MD * 2;   // 64 MiB total

    float* outp = (float*)d_out;
    float* attn_out = outp + MD;

    // 1) convert inputs + weights to bf16
    convk<<<dim3(4096, 3), 256, 0, stream>>>(query, key, value, nullptr, xq, xk, xv, nullptr, (int)MD);
    convk<<<dim3(1024, 4), 256, 0, stream>>>(Wq, Wk, Wv, Wo, wqb, wkb, wvb, wob, (int)DD);

    // 2) projections (x @ W^T + b), written in per-head layouts
    gemm_bt<1><<<dim3(32, 8), 256, 0, stream>>>(xq, wqb, bq, nullptr, qh, M, dmodel, dmodel);
    gemm_bt<1><<<dim3(32, 8), 256, 0, stream>>>(xk, wkb, bk, nullptr, kh, M, dmodel, dmodel);
    gemm_bt<2><<<dim3(32, 8), 256, 0, stream>>>(xv, wvb, bv, nullptr, vt, M, dmodel, dmodel);

    // 3) fused forget-attention (writes attn f32 + ctx bf16)
    size_t lds = 16 * 1034 * 4 + 16 * 1032 * 2 + 16 * 72 * 2;   // 101,504 B
    attn_fused<<<dim3(64, 64), 256, lds, stream>>>(qh, kh, vt, gammas, attn_out, ctx);

    // 4) output projection (ctx @ Wo^T + bo) -> f32
    gemm_bt<0><<<dim3(32, 8), 256, 0, stream>>>(ctx, wob, bo, outp, nullptr, M, dmodel, dmodel);
}

// Round 2
// 314.004 us; speedup vs baseline: 2.1383x; 2.1383x over previous
//
#include <hip/hip_runtime.h>
#include <hip/hip_bf16.h>

typedef __attribute__((ext_vector_type(8))) short short8;
typedef __attribute__((ext_vector_type(4))) float f32x4;
typedef __attribute__((ext_vector_type(4))) unsigned short us4;

#define MFMA(a, b, c) __builtin_amdgcn_mfma_f32_16x16x32_bf16((a), (b), (c), 0, 0, 0)

static __device__ inline unsigned short f2b(float f) {
    __hip_bfloat16 h = __float2bfloat16(f);
    return *reinterpret_cast<unsigned short*>(&h);
}

// ---------------- f32 -> bf16 conversion (up to 4 tensors via grid.y) ----------------
__global__ __launch_bounds__(256) void convk(
    const float* __restrict__ a, const float* __restrict__ b,
    const float* __restrict__ c, const float* __restrict__ dd,
    unsigned short* oa, unsigned short* ob, unsigned short* oc, unsigned short* od, int n)
{
    const float* in; unsigned short* out;
    switch (blockIdx.y) {
        case 0: in = a; out = oa; break;
        case 1: in = b; out = ob; break;
        case 2: in = c; out = oc; break;
        default: in = dd; out = od; break;
    }
    int i = (blockIdx.x * 256 + threadIdx.x) * 4;
    if (i >= n) return;
    float4 v = *(const float4*)(in + i);
    us4 o;
    o[0] = f2b(v.x); o[1] = f2b(v.y); o[2] = f2b(v.z); o[3] = f2b(v.w);
    *(us4*)(out + i) = o;
}

// ---------------- bf16 GEMM, C = A * B^T (+bias), templated epilogue ----------------
template<int EMODE>
__global__ __launch_bounds__(256) void gemm_bt(
    const unsigned short* __restrict__ A,
    const unsigned short* __restrict__ Bm,
    const float* __restrict__ bias,
    float* __restrict__ Cf,
    unsigned short* __restrict__ Cb,
    int M, int N, int K)
{
    __shared__ unsigned short sA[128 * 40];  // stride 40 = 32 + 8 pad
    __shared__ unsigned short sB[128 * 40];
    const int tid = threadIdx.x;
    const int wave = tid >> 6, lane = tid & 63;
    const int wm = (wave >> 1) * 64, wn = (wave & 1) * 64;
    const int bm = blockIdx.x * 128, bn = blockIdx.y * 128;
    const int fr = lane & 15, fg = lane >> 4;

    f32x4 acc[4][4] = {};

    for (int kt = 0; kt < K; kt += 32) {
        __syncthreads();
        #pragma unroll
        for (int i = 0; i < 2; ++i) {
            int idx = tid + i * 256;        // 0..511
            int r = idx >> 2, c = (idx & 3) * 8;
            *(short8*)&sA[r * 40 + c] = *(const short8*)&A[(size_t)(bm + r) * K + kt + c];
            *(short8*)&sB[r * 40 + c] = *(const short8*)&Bm[(size_t)(bn + r) * K + kt + c];
        }
        __syncthreads();
        short8 af[4], bf[4];
        #pragma unroll
        for (int mr = 0; mr < 4; ++mr) af[mr] = *(const short8*)&sA[(wm + mr * 16 + fr) * 40 + fg * 8];
        #pragma unroll
        for (int nr = 0; nr < 4; ++nr) bf[nr] = *(const short8*)&sB[(wn + nr * 16 + fr) * 40 + fg * 8];
        #pragma unroll
        for (int mr = 0; mr < 4; ++mr)
            #pragma unroll
            for (int nr = 0; nr < 4; ++nr)
                acc[mr][nr] = MFMA(af[mr], bf[nr], acc[mr][nr]);
    }

    #pragma unroll
    for (int mr = 0; mr < 4; ++mr)
        #pragma unroll
        for (int nr = 0; nr < 4; ++nr)
            #pragma unroll
            for (int j = 0; j < 4; ++j) {
                int m = bm + wm + mr * 16 + fg * 4 + j;
                int n = bn + wn + nr * 16 + fr;
                float v = acc[mr][nr][j] + bias[n];
                if (EMODE == 0) {
                    Cf[(size_t)m * N + n] = v;
                } else if (EMODE == 1) {
                    int b = m >> 10, s = m & 1023, h = n >> 6, dc = n & 63;
                    Cb[(((size_t)(b * 16 + h)) * 1024 + s) * 64 + dc] = f2b(v);
                } else {
                    int b = m >> 10, s = m & 1023, h = n >> 6, dc = n & 63;
                    Cb[(((size_t)(b * 16 + h)) * 64 + dc) * 1024 + s] = f2b(v);
                }
            }
}

// ---------------- fused forget-attention ----------------
// grid (64, 64) remapped so each XCD owns 8 complete heads. One block: 16 q-rows.
__global__ __launch_bounds__(256) void attn_fused(
    const unsigned short* __restrict__ Qh,   // [BH,S,64] bf16
    const unsigned short* __restrict__ Kh,   // [BH,S,64] bf16
    const unsigned short* __restrict__ Vt,   // [BH,64,S] bf16
    const float* __restrict__ gammas,        // [16]
    float* __restrict__ attn_out,            // [BH,S,S] f32
    unsigned short* __restrict__ ctx)        // [B*S,1024] bf16
{
    extern __shared__ char smem[];
    const int RS = 1104;                               // row stride (f32); 1104%32==16 -> 2-way free
    float* s_s = (float*)smem;                         // [16][1104] scores -> e2 -> bf16 p (in place)
    unsigned short* s_q = (unsigned short*)(smem + 16 * RS * 4);      // [16][72]
    float* s_inv = (float*)(smem + 16 * RS * 4 + 16 * 72 * 2);        // [16]
    const int S = 1024;

    // XCD-aware remap: each mod-8 dispatch slot owns 8 full (b,h) heads
    int gid = blockIdx.y * gridDim.x + blockIdx.x;     // 0..4095
    int jj = gid >> 3;
    const int bh = (gid & 7) * 8 + (jj >> 6);
    const int qb = jj & 63;
    const int q0 = qb * 16;
    const int tid = threadIdx.x;
    const int wave = tid >> 6, lane = tid & 63, fr = lane & 15, fg = lane >> 4;

    // load Q tile [16][64]
    {
        int rr = tid >> 4, c4 = (tid & 15) * 4;
        *(uint2*)&s_q[rr * 72 + c4] = *(const uint2*)&Qh[((size_t)bh * S + q0 + rr) * 64 + c4];
    }
    __syncthreads();
    const int kmax = q0 + 15;

    // phase 1: scores = QK^T / 8 into LDS (each wave: 256-col strip)
    {
        short8 qf0 = *(const short8*)&s_q[fr * 72 + fg * 8];
        short8 qf1 = *(const short8*)&s_q[fr * 72 + 32 + fg * 8];
        const unsigned short* kbase = &Kh[(size_t)bh * S * 64];
        for (int nf = 0; nf < 16; ++nf) {
            int cb = wave * 256 + nf * 16;
            if (cb > kmax) break;   // wave-uniform causal skip
            const unsigned short* kb = kbase + (size_t)cb * 64;
            short8 kf0 = *(const short8*)&kb[fr * 64 + fg * 8];
            short8 kf1 = *(const short8*)&kb[fr * 64 + 32 + fg * 8];
            f32x4 a = {0.f, 0.f, 0.f, 0.f};
            a = MFMA(qf0, kf0, a);
            a = MFMA(qf1, kf1, a);
            #pragma unroll
            for (int j = 0; j < 4; ++j)
                s_s[(size_t)(fg * 4 + j) * RS + cb + fr] = a[j] * 0.125f;
        }
    }
    __syncthreads();

    // phase 2: fused softmax->cumsum->decay->exp2, interleaved (conflict-free),
    // no max-subtraction (|s|<~8 -> f32-safe; softmax shift-invariant; te in [0.2,1])
    {
        const int r = tid >> 4, sub = tid & 15;
        const int qr = q0 + r;
        float* srow = &s_s[(size_t)r * RS];
        const float ag = fabsf(gammas[bh & 15]);
        const int iu = qr >> 4;

        // W1: T = sum exp(s)
        float ls = 0.f;
        for (int i = 0; i <= iu; ++i) {
            int kk = i * 16 + sub;
            if (kk <= qr) ls += __expf(srow[kk]);
        }
        #pragma unroll
        for (int m = 1; m < 16; m <<= 1) ls += __shfl_xor(ls, m, 16);
        const float T = ls, invT = 1.f / ls;

        // W2: rebuild running sum via 16-lane scan; decay; e2 = exp(s*te); store e2
        float carry = 0.f, ls2 = 0.f;
        for (int i = 0; i <= iu; ++i) {
            int kk = i * 16 + sub;
            bool act = kk <= qr;
            float s = srow[kk];
            float e = act ? __expf(s) : 0.f;
            float x = e, t;
            t = __shfl_up(x, 1, 16); if (sub >= 1) x += t;
            t = __shfl_up(x, 2, 16); if (sub >= 2) x += t;
            t = __shfl_up(x, 4, 16); if (sub >= 4) x += t;
            t = __shfl_up(x, 8, 16); if (sub >= 8) x += t;
            float run = carry + x;
            carry += __shfl(x, 15, 16);
            float rem = fmaxf(T - run, 0.f) * invT;          // (disttot - distcum)/T
            float dist = sqrtf(rem * (float)(qr - kk));
            float te = __expf(-ag * dist);
            float e2 = act ? __expf(s * te) : 0.f;
            srow[kk] = e2;
            ls2 += e2;
        }
        for (int i = iu + 1; i < 64; ++i) srow[i * 16 + sub] = 0.f;
        #pragma unroll
        for (int m = 1; m < 16; m <<= 1) ls2 += __shfl_xor(ls2, m, 16);
        if (sub == 0) s_inv[r] = 1.f / ls2;
    }
    __syncthreads();

    // phase 2b: vectorized attn write (nontemporal) + in-place bf16 p packing
    for (int rb = 0; rb < 4; ++rb) {
        f32x4 v[4];
        #pragma unroll
        for (int j = 0; j < 4; ++j)
            v[j] = *(const f32x4*)&s_s[(size_t)(rb * 4 + j) * RS + tid * 4];
        __syncthreads();   // all reads of this row-set done before in-place overwrite
        #pragma unroll
        for (int j = 0; j < 4; ++j) {
            int r = rb * 4 + j;
            float iv = s_inv[r];
            f32x4 w = v[j] * iv;
            __builtin_nontemporal_store(w,
                (f32x4*)(attn_out + ((size_t)bh * S + q0 + r) * S + tid * 4));
            us4 pk;
            pk[0] = f2b(w[0]); pk[1] = f2b(w[1]); pk[2] = f2b(w[2]); pk[3] = f2b(w[3]);
            *(us4*)((unsigned short*)&s_s[(size_t)r * RS] + tid * 4) = pk;
        }
    }
    __syncthreads();

    // phase 3: ctx = attn @ V  (each wave: 16 d-columns)
    {
        const unsigned short* vb = &Vt[(size_t)bh * 64 * S];
        f32x4 acc = {0.f, 0.f, 0.f, 0.f};
        const int ktiles = (kmax + 32) >> 5;
        const unsigned short* prow = (const unsigned short*)&s_s[(size_t)fr * RS];
        for (int kt = 0; kt < ktiles; ++kt) {
            short8 pa = *(const short8*)&prow[kt * 32 + fg * 8];
            short8 vf = *(const short8*)&vb[(size_t)(wave * 16 + fr) * S + kt * 32 + fg * 8];
            acc = MFMA(pa, vf, acc);
        }
        int b = bh >> 4, h = bh & 15;
        #pragma unroll
        for (int j = 0; j < 4; ++j)
            ctx[((size_t)b * S + q0 + fg * 4 + j) * 1024 + h * 64 + wave * 16 + fr] = f2b(acc[j]);
    }
}

extern "C" void kernel_launch(void* const* d_in, const int* in_sizes, int n_in,
                              void* d_out, int out_size, void* d_ws, size_t ws_size,
                              hipStream_t stream) {
    const float* query  = (const float*)d_in[0];
    const float* key    = (const float*)d_in[1];
    const float* value  = (const float*)d_in[2];
    const float* Wq = (const float*)d_in[4];
    const float* bq = (const float*)d_in[5];
    const float* Wk = (const float*)d_in[6];
    const float* bk = (const float*)d_in[7];
    const float* Wv = (const float*)d_in[8];
    const float* bv = (const float*)d_in[9];
    const float* Wo = (const float*)d_in[10];
    const float* bo = (const float*)d_in[11];
    const float* gammas = (const float*)d_in[12];

    const int S = 1024, dmodel = 1024;
    const int M = 4 * S;
    const size_t MD = (size_t)M * dmodel;
    const size_t DD = (size_t)dmodel * dmodel;

    char* ws = (char*)d_ws;
    unsigned short* xq  = (unsigned short*)ws;            ws += MD * 2;
    unsigned short* xk  = (unsigned short*)ws;            ws += MD * 2;
    unsigned short* xv  = (unsigned short*)ws;            ws += MD * 2;
    unsigned short* wqb = (unsigned short*)ws;            ws += DD * 2;
    unsigned short* wkb = (unsigned short*)ws;            ws += DD * 2;
    unsigned short* wvb = (unsigned short*)ws;            ws += DD * 2;
    unsigned short* wob = (unsigned short*)ws;            ws += DD * 2;
    unsigned short* qh  = (unsigned short*)ws;            ws += MD * 2;
    unsigned short* kh  = (unsigned short*)ws;            ws += MD * 2;
    unsigned short* vt  = (unsigned short*)ws;            ws += MD * 2;
    unsigned short* ctx = (unsigned short*)ws;            ws += MD * 2;

    float* outp = (float*)d_out;
    float* attn_out = outp + MD;

    convk<<<dim3(4096, 3), 256, 0, stream>>>(query, key, value, nullptr, xq, xk, xv, nullptr, (int)MD);
    convk<<<dim3(1024, 4), 256, 0, stream>>>(Wq, Wk, Wv, Wo, wqb, wkb, wvb, wob, (int)DD);

    gemm_bt<1><<<dim3(32, 8), 256, 0, stream>>>(xq, wqb, bq, nullptr, qh, M, dmodel, dmodel);
    gemm_bt<1><<<dim3(32, 8), 256, 0, stream>>>(xk, wkb, bk, nullptr, kh, M, dmodel, dmodel);
    gemm_bt<2><<<dim3(32, 8), 256, 0, stream>>>(xv, wvb, bv, nullptr, vt, M, dmodel, dmodel);

    size_t lds = 16 * 1104 * 4 + 16 * 72 * 2 + 16 * 4;   // 73,024 B -> 2 blocks/CU
    attn_fused<<<dim3(64, 64), 256, lds, stream>>>(qh, kh, vt, gammas, attn_out, ctx);

    gemm_bt<0><<<dim3(32, 8), 256, 0, stream>>>(ctx, wob, bo, outp, nullptr, M, dmodel, dmodel);
}

// Round 3
// 250.784 us; speedup vs baseline: 2.6773x; 1.2521x over previous
//
#include <hip/hip_runtime.h>
#include <hip/hip_bf16.h>

typedef __attribute__((ext_vector_type(8))) short short8;
typedef __attribute__((ext_vector_type(4))) float f32x4;
typedef __attribute__((ext_vector_type(4))) unsigned short us4;

#define MFMA(a, b, c) __builtin_amdgcn_mfma_f32_16x16x32_bf16((a), (b), (c), 0, 0, 0)

static __device__ inline unsigned short f2b(float f) {
    __hip_bfloat16 h = __float2bfloat16(f);
    return *reinterpret_cast<unsigned short*>(&h);
}

// ---------------- f32 -> bf16 conversion (up to 4 tensors via grid.y) ----------------
__global__ __launch_bounds__(256) void convk(
    const float* __restrict__ a, const float* __restrict__ b,
    const float* __restrict__ c, const float* __restrict__ dd,
    unsigned short* oa, unsigned short* ob, unsigned short* oc, unsigned short* od, int n)
{
    const float* in; unsigned short* out;
    switch (blockIdx.y) {
        case 0: in = a; out = oa; break;
        case 1: in = b; out = ob; break;
        case 2: in = c; out = oc; break;
        default: in = dd; out = od; break;
    }
    int i = (blockIdx.x * 256 + threadIdx.x) * 4;
    if (i >= n) return;
    float4 v = *(const float4*)(in + i);
    us4 o;
    o[0] = f2b(v.x); o[1] = f2b(v.y); o[2] = f2b(v.z); o[3] = f2b(v.w);
    *(us4*)(out + i) = o;
}

// ---------------- bf16 GEMM, C = A * B^T (+bias), templated epilogue ----------------
template<int EMODE>
__global__ __launch_bounds__(256) void gemm_bt(
    const unsigned short* __restrict__ A,
    const unsigned short* __restrict__ Bm,
    const float* __restrict__ bias,
    float* __restrict__ Cf,
    unsigned short* __restrict__ Cb,
    int M, int N, int K)
{
    __shared__ unsigned short sA[128 * 40];  // stride 40 = 32 + 8 pad
    __shared__ unsigned short sB[128 * 40];
    const int tid = threadIdx.x;
    const int wave = tid >> 6, lane = tid & 63;
    const int wm = (wave >> 1) * 64, wn = (wave & 1) * 64;
    const int bm = blockIdx.x * 128, bn = blockIdx.y * 128;
    const int fr = lane & 15, fg = lane >> 4;

    f32x4 acc[4][4] = {};

    for (int kt = 0; kt < K; kt += 32) {
        __syncthreads();
        #pragma unroll
        for (int i = 0; i < 2; ++i) {
            int idx = tid + i * 256;        // 0..511
            int r = idx >> 2, c = (idx & 3) * 8;
            *(short8*)&sA[r * 40 + c] = *(const short8*)&A[(size_t)(bm + r) * K + kt + c];
            *(short8*)&sB[r * 40 + c] = *(const short8*)&Bm[(size_t)(bn + r) * K + kt + c];
        }
        __syncthreads();
        short8 af[4], bf[4];
        #pragma unroll
        for (int mr = 0; mr < 4; ++mr) af[mr] = *(const short8*)&sA[(wm + mr * 16 + fr) * 40 + fg * 8];
        #pragma unroll
        for (int nr = 0; nr < 4; ++nr) bf[nr] = *(const short8*)&sB[(wn + nr * 16 + fr) * 40 + fg * 8];
        #pragma unroll
        for (int mr = 0; mr < 4; ++mr)
            #pragma unroll
            for (int nr = 0; nr < 4; ++nr)
                acc[mr][nr] = MFMA(af[mr], bf[nr], acc[mr][nr]);
    }

    #pragma unroll
    for (int mr = 0; mr < 4; ++mr)
        #pragma unroll
        for (int nr = 0; nr < 4; ++nr)
            #pragma unroll
            for (int j = 0; j < 4; ++j) {
                int m = bm + wm + mr * 16 + fg * 4 + j;
                int n = bn + wn + nr * 16 + fr;
                float v = acc[mr][nr][j] + bias[n];
                if (EMODE == 0) {
                    Cf[(size_t)m * N + n] = v;
                } else if (EMODE == 1) {
                    int b = m >> 10, s = m & 1023, h = n >> 6, dc = n & 63;
                    Cb[(((size_t)(b * 16 + h)) * 1024 + s) * 64 + dc] = f2b(v);
                } else {
                    int b = m >> 10, s = m & 1023, h = n >> 6, dc = n & 63;
                    Cb[(((size_t)(b * 16 + h)) * 64 + dc) * 1024 + s] = f2b(v);
                }
            }
}

// ---------------- fused forget-attention ----------------
// grid (64, 64) remapped so each XCD owns 8 complete heads. One block: 16 q-rows.
__global__ __launch_bounds__(256) void attn_fused(
    const unsigned short* __restrict__ Qh,   // [BH,S,64] bf16
    const unsigned short* __restrict__ Kh,   // [BH,S,64] bf16
    const unsigned short* __restrict__ Vt,   // [BH,64,S] bf16
    const float* __restrict__ gammas,        // [16]
    float* __restrict__ attn_out,            // [BH,S,S] f32
    unsigned short* __restrict__ ctx)        // [B*S,1024] bf16
{
    extern __shared__ char smem[];
    const int RS = 1104;                               // row stride (f32)
    float* s_s = (float*)smem;                         // [16][1104] scores -> e2 -> bf16 p (in place)
    unsigned short* s_q = (unsigned short*)(smem + 16 * RS * 4);      // [16][72]
    float* s_inv = (float*)(smem + 16 * RS * 4 + 16 * 72 * 2);        // [16]
    const int S = 1024;

    // XCD-aware remap: each mod-8 dispatch slot owns 8 full (b,h) heads
    int gid = blockIdx.y * gridDim.x + blockIdx.x;     // 0..4095
    int jj = gid >> 3;
    const int bh = (gid & 7) * 8 + (jj >> 6);
    const int qb = jj & 63;
    const int q0 = qb * 16;
    const int tid = threadIdx.x;
    const int wave = tid >> 6, lane = tid & 63, fr = lane & 15, fg = lane >> 4;

    // load Q tile [16][64]
    {
        int rr = tid >> 4, c4 = (tid & 15) * 4;
        *(uint2*)&s_q[rr * 72 + c4] = *(const uint2*)&Qh[((size_t)bh * S + q0 + rr) * 64 + c4];
    }
    __syncthreads();
    const int kmax = q0 + 15;

    // phase 1: scores = QK^T / 8 into LDS (each wave: 256-col strip)
    {
        short8 qf0 = *(const short8*)&s_q[fr * 72 + fg * 8];
        short8 qf1 = *(const short8*)&s_q[fr * 72 + 32 + fg * 8];
        const unsigned short* kbase = &Kh[(size_t)bh * S * 64];
        for (int nf = 0; nf < 16; ++nf) {
            int cb = wave * 256 + nf * 16;
            if (cb > kmax) break;   // wave-uniform causal skip
            const unsigned short* kb = kbase + (size_t)cb * 64;
            short8 kf0 = *(const short8*)&kb[fr * 64 + fg * 8];
            short8 kf1 = *(const short8*)&kb[fr * 64 + 32 + fg * 8];
            f32x4 a = {0.f, 0.f, 0.f, 0.f};
            a = MFMA(qf0, kf0, a);
            a = MFMA(qf1, kf1, a);
            #pragma unroll
            for (int j = 0; j < 4; ++j)
                s_s[(size_t)(fg * 4 + j) * RS + cb + fr] = a[j] * 0.125f;
        }
    }
    __syncthreads();

    // phase 2: fused softmax->cumsum->decay->exp2.
    // Each of 16 lanes owns a CONTIGUOUS segment of L = 4m (m odd -> stride-L
    // f32x4 accesses spread across bank groups, conflict-free). One cross-lane
    // scan per ROW (not per 16 elements) -> no serial shfl chain in the loop.
    // No max-subtraction (|s|<~8 f32-safe; softmax shift-invariant).
    {
        const int r = tid >> 4, sub = tid & 15;
        const int qr = q0 + r;
        float* srow = &s_s[(size_t)r * RS];
        const float ag = fabsf(gammas[bh & 15]);
        const int m = ((qb + 4) >> 2) | 1;     // ceil((qb+1)/4), forced odd
        const int L = 4 * m;                   // 16*L >= q0+16 > qr
        const int base = sub * L;

        // pass (a): segment sums of e = exp(s)
        float seg = 0.f;
        for (int c = 0; c < m; ++c) {
            f32x4 s4 = *(const f32x4*)&srow[base + c * 4];
            #pragma unroll
            for (int j = 0; j < 4; ++j) {
                int kk = base + c * 4 + j;
                seg += (kk <= qr) ? __expf(s4[j]) : 0.f;
            }
        }
        // one inclusive scan over the 16 segment sums
        float x = seg, t;
        t = __shfl_up(x, 1, 16); if (sub >= 1) x += t;
        t = __shfl_up(x, 2, 16); if (sub >= 2) x += t;
        t = __shfl_up(x, 4, 16); if (sub >= 4) x += t;
        t = __shfl_up(x, 8, 16); if (sub >= 8) x += t;
        const float T = __shfl(x, 15, 16);
        const float invT = 1.f / T;
        float run = x - seg;                   // exclusive prefix

        // pass (b): decay + second exp, store e2 (unnormalized)
        float ls2 = 0.f;
        for (int c = 0; c < m; ++c) {
            f32x4 s4 = *(const f32x4*)&srow[base + c * 4];
            f32x4 o;
            #pragma unroll
            for (int j = 0; j < 4; ++j) {
                int kk = base + c * 4 + j;
                bool act = kk <= qr;
                float e = act ? __expf(s4[j]) : 0.f;
                run += e;
                float rem = fmaxf(T - run, 0.f) * invT;      // (disttot - distcum)/T
                float dist = sqrtf(rem * (float)(qr - kk));
                float te = __expf(-ag * dist);
                float e2 = act ? __expf(s4[j] * te) : 0.f;
                o[j] = e2;
                ls2 += e2;
            }
            *(f32x4*)&srow[base + c * 4] = o;
        }
        // zero tail [16L, 1024) (chunks of 4 f32)
        for (int c = (L << 2) + sub; c < 256; c += 16)
            *(f32x4*)&srow[c * 4] = (f32x4){0.f, 0.f, 0.f, 0.f};
        #pragma unroll
        for (int mm = 1; mm < 16; mm <<= 1) ls2 += __shfl_xor(ls2, mm, 16);
        if (sub == 0) s_inv[r] = 1.f / ls2;
    }
    __syncthreads();

    // phase 2b: vectorized attn write (nontemporal) + in-place bf16 p packing
    for (int rb = 0; rb < 4; ++rb) {
        f32x4 v[4];
        #pragma unroll
        for (int j = 0; j < 4; ++j)
            v[j] = *(const f32x4*)&s_s[(size_t)(rb * 4 + j) * RS + tid * 4];
        __syncthreads();   // all reads of this row-set done before in-place overwrite
        #pragma unroll
        for (int j = 0; j < 4; ++j) {
            int r = rb * 4 + j;
            float iv = s_inv[r];
            f32x4 w = v[j] * iv;
            __builtin_nontemporal_store(w,
                (f32x4*)(attn_out + ((size_t)bh * S + q0 + r) * S + tid * 4));
            us4 pk;
            pk[0] = f2b(w[0]); pk[1] = f2b(w[1]); pk[2] = f2b(w[2]); pk[3] = f2b(w[3]);
            *(us4*)((unsigned short*)&s_s[(size_t)r * RS] + tid * 4) = pk;
        }
    }
    __syncthreads();

    // phase 3: ctx = attn @ V  (each wave: 16 d-columns)
    {
        const unsigned short* vb = &Vt[(size_t)bh * 64 * S];
        f32x4 acc = {0.f, 0.f, 0.f, 0.f};
        const int ktiles = (kmax + 32) >> 5;
        const unsigned short* prow = (const unsigned short*)&s_s[(size_t)fr * RS];
        for (int kt = 0; kt < ktiles; ++kt) {
            short8 pa = *(const short8*)&prow[kt * 32 + fg * 8];
            short8 vf = *(const short8*)&vb[(size_t)(wave * 16 + fr) * S + kt * 32 + fg * 8];
            acc = MFMA(pa, vf, acc);
        }
        int b = bh >> 4, h = bh & 15;
        #pragma unroll
        for (int j = 0; j < 4; ++j)
            ctx[((size_t)b * S + q0 + fg * 4 + j) * 1024 + h * 64 + wave * 16 + fr] = f2b(acc[j]);
    }
}

extern "C" void kernel_launch(void* const* d_in, const int* in_sizes, int n_in,
                              void* d_out, int out_size, void* d_ws, size_t ws_size,
                              hipStream_t stream) {
    const float* query  = (const float*)d_in[0];
    const float* key    = (const float*)d_in[1];
    const float* value  = (const float*)d_in[2];
    const float* Wq = (const float*)d_in[4];
    const float* bq = (const float*)d_in[5];
    const float* Wk = (const float*)d_in[6];
    const float* bk = (const float*)d_in[7];
    const float* Wv = (const float*)d_in[8];
    const float* bv = (const float*)d_in[9];
    const float* Wo = (const float*)d_in[10];
    const float* bo = (const float*)d_in[11];
    const float* gammas = (const float*)d_in[12];

    const int S = 1024, dmodel = 1024;
    const int M = 4 * S;
    const size_t MD = (size_t)M * dmodel;
    const size_t DD = (size_t)dmodel * dmodel;

    char* ws = (char*)d_ws;
    unsigned short* xq  = (unsigned short*)ws;            ws += MD * 2;
    unsigned short* xk  = (unsigned short*)ws;            ws += MD * 2;
    unsigned short* xv  = (unsigned short*)ws;            ws += MD * 2;
    unsigned short* wqb = (unsigned short*)ws;            ws += DD * 2;
    unsigned short* wkb = (unsigned short*)ws;            ws += DD * 2;
    unsigned short* wvb = (unsigned short*)ws;            ws += DD * 2;
    unsigned short* wob = (unsigned short*)ws;            ws += DD * 2;
    unsigned short* qh  = (unsigned short*)ws;            ws += MD * 2;
    unsigned short* kh  = (unsigned short*)ws;            ws += MD * 2;
    unsigned short* vt  = (unsigned short*)ws;            ws += MD * 2;
    unsigned short* ctx = (unsigned short*)ws;            ws += MD * 2;

    float* outp = (float*)d_out;
    float* attn_out = outp + MD;

    convk<<<dim3(4096, 3), 256, 0, stream>>>(query, key, value, nullptr, xq, xk, xv, nullptr, (int)MD);
    convk<<<dim3(1024, 4), 256, 0, stream>>>(Wq, Wk, Wv, Wo, wqb, wkb, wvb, wob, (int)DD);

    gemm_bt<1><<<dim3(32, 8), 256, 0, stream>>>(xq, wqb, bq, nullptr, qh, M, dmodel, dmodel);
    gemm_bt<1><<<dim3(32, 8), 256, 0, stream>>>(xk, wkb, bk, nullptr, kh, M, dmodel, dmodel);
    gemm_bt<2><<<dim3(32, 8), 256, 0, stream>>>(xv, wvb, bv, nullptr, vt, M, dmodel, dmodel);

    size_t lds = 16 * 1104 * 4 + 16 * 72 * 2 + 16 * 4;   // 73,024 B -> 2 blocks/CU
    attn_fused<<<dim3(64, 64), 256, lds, stream>>>(qh, kh, vt, gammas, attn_out, ctx);

    gemm_bt<0><<<dim3(32, 8), 256, 0, stream>>>(ctx, wob, bo, outp, nullptr, M, dmodel, dmodel);
}

// Round 4
// 223.681 us; speedup vs baseline: 3.0017x; 1.1212x over previous
//
#include <hip/hip_runtime.h>
#include <hip/hip_bf16.h>

typedef __attribute__((ext_vector_type(8))) short short8;
typedef __attribute__((ext_vector_type(4))) float f32x4;
typedef __attribute__((ext_vector_type(4))) unsigned short us4;

#define MFMA(a, b, c) __builtin_amdgcn_mfma_f32_16x16x32_bf16((a), (b), (c), 0, 0, 0)

static __device__ inline unsigned short f2b(float f) {
    __hip_bfloat16 h = __float2bfloat16(f);
    return *reinterpret_cast<unsigned short*>(&h);
}

// async global->LDS, 16B per lane. LDS dst must be wave-uniform base; HW adds lane*16.
static __device__ __forceinline__ void gload_lds16(const unsigned short* g, unsigned short* s) {
    __builtin_amdgcn_global_load_lds(
        (const __attribute__((address_space(1))) unsigned int*)(g),
        (__attribute__((address_space(3))) unsigned int*)(s),
        16, 0, 0);
}

// ---------------- f32 -> bf16 conversion (up to 4 tensors via grid.y) ----------------
__global__ __launch_bounds__(256) void convk(
    const float* __restrict__ a, const float* __restrict__ b,
    const float* __restrict__ c, const float* __restrict__ dd,
    unsigned short* oa, unsigned short* ob, unsigned short* oc, unsigned short* od, int n)
{
    const float* in; unsigned short* out;
    switch (blockIdx.y) {
        case 0: in = a; out = oa; break;
        case 1: in = b; out = ob; break;
        case 2: in = c; out = oc; break;
        default: in = dd; out = od; break;
    }
    int i = (blockIdx.x * 256 + threadIdx.x) * 4;
    if (i >= n) return;
    float4 v = *(const float4*)(in + i);
    us4 o;
    o[0] = f2b(v.x); o[1] = f2b(v.y); o[2] = f2b(v.z); o[3] = f2b(v.w);
    *(us4*)(out + i) = o;
}

// ---------------- bf16 GEMM (m97 structure), C = A * B^T (+bias) ----------------
// BM=64, BN=128, BK=32, 256 threads (4 waves, 2x2), global_load_lds staging.
// A [M,K] bf16 row-major, Bm [N,K] bf16 row-major.
// EMODE 0: f32 row-major out. 1: bf16 [B,H,S,dk]. 2: bf16 [B,H,dk,S].
template<int EMODE>
__global__ __launch_bounds__(256) void gemm_bt(
    const unsigned short* __restrict__ A,
    const unsigned short* __restrict__ Bm,
    const float* __restrict__ bias,
    float* __restrict__ Cf,
    unsigned short* __restrict__ Cb,
    int M, int N, int K)
{
    __shared__ unsigned short sA[64 * 32];    // linear, no pad (global_load_lds)
    __shared__ unsigned short sB[128 * 32];
    const int tid = threadIdx.x;
    const int wave = tid >> 6, lane = tid & 63;
    const int wm = (wave >> 1) * 32, wn = (wave & 1) * 64;
    const int bm = blockIdx.x * 64, bn = blockIdx.y * 128;
    const int fr = lane & 15, fg = lane >> 4;

    // staging source addresses (per-lane): row = lane>>2 within issue, chunk = lane&3
    const int srow = lane >> 2, schk = (lane & 3) * 8;
    const unsigned short* Ab = A + (size_t)(bm + wave * 16 + srow) * K + schk;
    const unsigned short* Bb0 = Bm + (size_t)(bn + wave * 32 + srow) * K + schk;
    const unsigned short* Bb1 = Bb0 + (size_t)16 * K;
    unsigned short* sAw  = &sA[(wave * 16) * 32];
    unsigned short* sBw0 = &sB[(wave * 32) * 32];
    unsigned short* sBw1 = &sB[(wave * 32 + 16) * 32];

    f32x4 acc[2][4] = {};

    for (int kt = 0; kt < K; kt += 32) {
        __syncthreads();                      // protect prior ds_reads
        gload_lds16(Ab + kt, sAw);
        gload_lds16(Bb0 + kt, sBw0);
        gload_lds16(Bb1 + kt, sBw1);
        __syncthreads();                      // drains vmcnt (loads landed)
        short8 af[2], bf[4];
        #pragma unroll
        for (int mr = 0; mr < 2; ++mr) af[mr] = *(const short8*)&sA[(wm + mr * 16 + fr) * 32 + fg * 8];
        #pragma unroll
        for (int nr = 0; nr < 4; ++nr) bf[nr] = *(const short8*)&sB[(wn + nr * 16 + fr) * 32 + fg * 8];
        #pragma unroll
        for (int mr = 0; mr < 2; ++mr)
            #pragma unroll
            for (int nr = 0; nr < 4; ++nr)
                acc[mr][nr] = MFMA(af[mr], bf[nr], acc[mr][nr]);
    }

    #pragma unroll
    for (int mr = 0; mr < 2; ++mr)
        #pragma unroll
        for (int nr = 0; nr < 4; ++nr)
            #pragma unroll
            for (int j = 0; j < 4; ++j) {
                int m = bm + wm + mr * 16 + fg * 4 + j;
                int n = bn + wn + nr * 16 + fr;
                float v = acc[mr][nr][j] + bias[n];
                if (EMODE == 0) {
                    Cf[(size_t)m * N + n] = v;
                } else if (EMODE == 1) {
                    int b = m >> 10, s = m & 1023, h = n >> 6, dc = n & 63;
                    Cb[(((size_t)(b * 16 + h)) * 1024 + s) * 64 + dc] = f2b(v);
                } else {
                    int b = m >> 10, s = m & 1023, h = n >> 6, dc = n & 63;
                    Cb[(((size_t)(b * 16 + h)) * 64 + dc) * 1024 + s] = f2b(v);
                }
            }
}

// ---------------- fused forget-attention ----------------
// grid (64, 64) remapped so each XCD owns 8 complete heads. One block: 16 q-rows.
__global__ __launch_bounds__(256) void attn_fused(
    const unsigned short* __restrict__ Qh,   // [BH,S,64] bf16
    const unsigned short* __restrict__ Kh,   // [BH,S,64] bf16
    const unsigned short* __restrict__ Vt,   // [BH,64,S] bf16
    const float* __restrict__ gammas,        // [16]
    float* __restrict__ attn_out,            // [BH,S,S] f32
    unsigned short* __restrict__ ctx)        // [B*S,1024] bf16
{
    extern __shared__ char smem[];
    const int RS = 1104;                               // row stride (f32)
    float* s_s = (float*)smem;                         // [16][1104] scores -> e2 -> bf16 p (in place)
    unsigned short* s_q = (unsigned short*)(smem + 16 * RS * 4);      // [16][72]
    float* s_inv = (float*)(smem + 16 * RS * 4 + 16 * 72 * 2);        // [16]
    const int S = 1024;

    // XCD-aware remap: each mod-8 dispatch slot owns 8 full (b,h) heads
    int gid = blockIdx.y * gridDim.x + blockIdx.x;     // 0..4095
    int jj = gid >> 3;
    const int bh = (gid & 7) * 8 + (jj >> 6);
    const int qb = jj & 63;
    const int q0 = qb * 16;
    const int tid = threadIdx.x;
    const int wave = tid >> 6, lane = tid & 63, fr = lane & 15, fg = lane >> 4;

    // load Q tile [16][64]
    {
        int rr = tid >> 4, c4 = (tid & 15) * 4;
        *(uint2*)&s_q[rr * 72 + c4] = *(const uint2*)&Qh[((size_t)bh * S + q0 + rr) * 64 + c4];
    }
    __syncthreads();
    const int kmax = q0 + 15;

    // phase 1: scores = QK^T / 8 into LDS.
    // 16-col tiles interleaved across waves (cb = (nf*4+wave)*16) for causal load balance.
    {
        short8 qf0 = *(const short8*)&s_q[fr * 72 + fg * 8];
        short8 qf1 = *(const short8*)&s_q[fr * 72 + 32 + fg * 8];
        const unsigned short* kbase = &Kh[(size_t)bh * S * 64];
        for (int nf = 0; nf < 16; ++nf) {
            int cb = (nf * 4 + wave) * 16;
            if (cb > kmax) break;   // wave-uniform causal skip
            const unsigned short* kb = kbase + (size_t)cb * 64;
            short8 kf0 = *(const short8*)&kb[fr * 64 + fg * 8];
            short8 kf1 = *(const short8*)&kb[fr * 64 + 32 + fg * 8];
            f32x4 a = {0.f, 0.f, 0.f, 0.f};
            a = MFMA(qf0, kf0, a);
            a = MFMA(qf1, kf1, a);
            #pragma unroll
            for (int j = 0; j < 4; ++j)
                s_s[(size_t)(fg * 4 + j) * RS + cb + fr] = a[j] * 0.125f;
        }
    }
    __syncthreads();

    // phase 2: fused softmax->cumsum->decay->exp2.
    // Each of 16 lanes owns a CONTIGUOUS segment of L = 4m (m odd -> stride-L
    // f32x4 accesses spread across bank groups). One cross-lane scan per ROW.
    // No max-subtraction (|s|<~8 f32-safe; softmax shift-invariant).
    {
        const int r = tid >> 4, sub = tid & 15;
        const int qr = q0 + r;
        float* srow = &s_s[(size_t)r * RS];
        const float ag = fabsf(gammas[bh & 15]);
        const int m = ((qb + 4) >> 2) | 1;     // ceil((qb+1)/4), forced odd
        const int L = 4 * m;                   // 16*L >= q0+16 > qr
        const int base = sub * L;

        // pass (a): segment sums of e = exp(s)
        float seg = 0.f;
        for (int c = 0; c < m; ++c) {
            f32x4 s4 = *(const f32x4*)&srow[base + c * 4];
            #pragma unroll
            for (int j = 0; j < 4; ++j) {
                int kk = base + c * 4 + j;
                seg += (kk <= qr) ? __expf(s4[j]) : 0.f;
            }
        }
        // one inclusive scan over the 16 segment sums
        float x = seg, t;
        t = __shfl_up(x, 1, 16); if (sub >= 1) x += t;
        t = __shfl_up(x, 2, 16); if (sub >= 2) x += t;
        t = __shfl_up(x, 4, 16); if (sub >= 4) x += t;
        t = __shfl_up(x, 8, 16); if (sub >= 8) x += t;
        const float T = __shfl(x, 15, 16);
        const float invT = 1.f / T;
        float run = x - seg;                   // exclusive prefix

        // pass (b): decay + second exp, store e2 (unnormalized)
        float ls2 = 0.f;
        for (int c = 0; c < m; ++c) {
            f32x4 s4 = *(const f32x4*)&srow[base + c * 4];
            f32x4 o;
            #pragma unroll
            for (int j = 0; j < 4; ++j) {
                int kk = base + c * 4 + j;
                bool act = kk <= qr;
                float e = act ? __expf(s4[j]) : 0.f;
                run += e;
                float rem = fmaxf(T - run, 0.f) * invT;      // (disttot - distcum)/T
                float dist = sqrtf(rem * (float)(qr - kk));
                float te = __expf(-ag * dist);
                float e2 = act ? __expf(s4[j] * te) : 0.f;
                o[j] = e2;
                ls2 += e2;
            }
            *(f32x4*)&srow[base + c * 4] = o;
        }
        // zero tail [16L, 1024) (chunks of 4 f32)
        for (int c = (L << 2) + sub; c < 256; c += 16)
            *(f32x4*)&srow[c * 4] = (f32x4){0.f, 0.f, 0.f, 0.f};
        #pragma unroll
        for (int mm = 1; mm < 16; mm <<= 1) ls2 += __shfl_xor(ls2, mm, 16);
        if (sub == 0) s_inv[r] = 1.f / ls2;
    }
    __syncthreads();

    // phase 2b: vectorized attn write (nontemporal) + in-place bf16 p packing
    for (int rb = 0; rb < 4; ++rb) {
        f32x4 v[4];
        #pragma unroll
        for (int j = 0; j < 4; ++j)
            v[j] = *(const f32x4*)&s_s[(size_t)(rb * 4 + j) * RS + tid * 4];
        __syncthreads();   // all reads of this row-set done before in-place overwrite
        #pragma unroll
        for (int j = 0; j < 4; ++j) {
            int r = rb * 4 + j;
            float iv = s_inv[r];
            f32x4 w = v[j] * iv;
            __builtin_nontemporal_store(w,
                (f32x4*)(attn_out + ((size_t)bh * S + q0 + r) * S + tid * 4));
            us4 pk;
            pk[0] = f2b(w[0]); pk[1] = f2b(w[1]); pk[2] = f2b(w[2]); pk[3] = f2b(w[3]);
            *(us4*)((unsigned short*)&s_s[(size_t)r * RS] + tid * 4) = pk;
        }
    }
    __syncthreads();

    // phase 3: ctx = attn @ V  (each wave: 16 d-columns)
    {
        const unsigned short* vb = &Vt[(size_t)bh * 64 * S];
        f32x4 acc = {0.f, 0.f, 0.f, 0.f};
        const int ktiles = (kmax + 32) >> 5;
        const unsigned short* prow = (const unsigned short*)&s_s[(size_t)fr * RS];
        for (int kt = 0; kt < ktiles; ++kt) {
            short8 pa = *(const short8*)&prow[kt * 32 + fg * 8];
            short8 vf = *(const short8*)&vb[(size_t)(wave * 16 + fr) * S + kt * 32 + fg * 8];
            acc = MFMA(pa, vf, acc);
        }
        int b = bh >> 4, h = bh & 15;
        #pragma unroll
        for (int j = 0; j < 4; ++j)
            ctx[((size_t)b * S + q0 + fg * 4 + j) * 1024 + h * 64 + wave * 16 + fr] = f2b(acc[j]);
    }
}

extern "C" void kernel_launch(void* const* d_in, const int* in_sizes, int n_in,
                              void* d_out, int out_size, void* d_ws, size_t ws_size,
                              hipStream_t stream) {
    const float* query  = (const float*)d_in[0];
    const float* key    = (const float*)d_in[1];
    const float* value  = (const float*)d_in[2];
    const float* Wq = (const float*)d_in[4];
    const float* bq = (const float*)d_in[5];
    const float* Wk = (const float*)d_in[6];
    const float* bk = (const float*)d_in[7];
    const float* Wv = (const float*)d_in[8];
    const float* bv = (const float*)d_in[9];
    const float* Wo = (const float*)d_in[10];
    const float* bo = (const float*)d_in[11];
    const float* gammas = (const float*)d_in[12];

    const int S = 1024, dmodel = 1024;
    const int M = 4 * S;
    const size_t MD = (size_t)M * dmodel;
    const size_t DD = (size_t)dmodel * dmodel;

    char* ws = (char*)d_ws;
    unsigned short* xq  = (unsigned short*)ws;            ws += MD * 2;
    unsigned short* xk  = (unsigned short*)ws;            ws += MD * 2;
    unsigned short* xv  = (unsigned short*)ws;            ws += MD * 2;
    unsigned short* wqb = (unsigned short*)ws;            ws += DD * 2;
    unsigned short* wkb = (unsigned short*)ws;            ws += DD * 2;
    unsigned short* wvb = (unsigned short*)ws;            ws += DD * 2;
    unsigned short* wob = (unsigned short*)ws;            ws += DD * 2;
    unsigned short* qh  = (unsigned short*)ws;            ws += MD * 2;
    unsigned short* kh  = (unsigned short*)ws;            ws += MD * 2;
    unsigned short* vt  = (unsigned short*)ws;            ws += MD * 2;
    unsigned short* ctx = (unsigned short*)ws;            ws += MD * 2;

    float* outp = (float*)d_out;
    float* attn_out = outp + MD;

    convk<<<dim3(4096, 3), 256, 0, stream>>>(query, key, value, nullptr, xq, xk, xv, nullptr, (int)MD);
    convk<<<dim3(1024, 4), 256, 0, stream>>>(Wq, Wk, Wv, Wo, wqb, wkb, wvb, wob, (int)DD);

    gemm_bt<1><<<dim3(64, 8), 256, 0, stream>>>(xq, wqb, bq, nullptr, qh, M, dmodel, dmodel);
    gemm_bt<1><<<dim3(64, 8), 256, 0, stream>>>(xk, wkb, bk, nullptr, kh, M, dmodel, dmodel);
    gemm_bt<2><<<dim3(64, 8), 256, 0, stream>>>(xv, wvb, bv, nullptr, vt, M, dmodel, dmodel);

    size_t lds = 16 * 1104 * 4 + 16 * 72 * 2 + 16 * 4;   // 73,024 B -> 2 blocks/CU
    attn_fused<<<dim3(64, 64), 256, lds, stream>>>(qh, kh, vt, gammas, attn_out, ctx);

    gemm_bt<0><<<dim3(64, 8), 256, 0, stream>>>(ctx, wob, bo, outp, nullptr, M, dmodel, dmodel);
}

// Round 5
// 195.012 us; speedup vs baseline: 3.4430x; 1.1470x over previous
//
#include <hip/hip_runtime.h>
#include <hip/hip_bf16.h>

typedef __attribute__((ext_vector_type(8))) short short8;
typedef __attribute__((ext_vector_type(4))) float f32x4;
typedef __attribute__((ext_vector_type(4))) unsigned short us4;

#define MFMA(a, b, c) __builtin_amdgcn_mfma_f32_16x16x32_bf16((a), (b), (c), 0, 0, 0)

static __device__ inline unsigned short f2b(float f) {
    __hip_bfloat16 h = __float2bfloat16(f);
    return *reinterpret_cast<unsigned short*>(&h);
}
static __device__ inline float b2f(unsigned short u) {
    unsigned int x = ((unsigned int)u) << 16;
    return __builtin_bit_cast(float, x);
}

// async global->LDS, 16B per lane. LDS dst must be wave-uniform base; HW adds lane*16.
static __device__ __forceinline__ void gload_lds16(const unsigned short* g, unsigned short* s) {
    __builtin_amdgcn_global_load_lds(
        (const __attribute__((address_space(1))) unsigned int*)(g),
        (__attribute__((address_space(3))) unsigned int*)(s),
        16, 0, 0);
}

// ---------------- f32 -> bf16 conversion (up to 4 tensors via grid.y) ----------------
__global__ __launch_bounds__(256) void convk(
    const float* __restrict__ a, const float* __restrict__ b,
    const float* __restrict__ c, const float* __restrict__ dd,
    unsigned short* oa, unsigned short* ob, unsigned short* oc, unsigned short* od, int n)
{
    const float* in; unsigned short* out;
    switch (blockIdx.y) {
        case 0: in = a; out = oa; break;
        case 1: in = b; out = ob; break;
        case 2: in = c; out = oc; break;
        default: in = dd; out = od; break;
    }
    int i = (blockIdx.x * 256 + threadIdx.x) * 4;
    if (i >= n) return;
    float4 v = *(const float4*)(in + i);
    us4 o;
    o[0] = f2b(v.x); o[1] = f2b(v.y); o[2] = f2b(v.z); o[3] = f2b(v.w);
    *(us4*)(out + i) = o;
}

// ---------------- bf16 GEMM, double-buffered 2-phase pipeline ----------------
// BM=64, BN=128, BK=32, 256 threads (4 waves 2x2), global_load_lds staging.
// Per iter: STAGE(buf^1, t+1) -> compute(buf) -> one barrier (T3 minimum recipe).
template<int EMODE>
__global__ __launch_bounds__(256) void gemm_bt(
    const unsigned short* __restrict__ A,
    const unsigned short* __restrict__ Bm,
    const float* __restrict__ bias,
    float* __restrict__ Cf,
    unsigned short* __restrict__ Cb,
    int M, int N, int K)
{
    __shared__ unsigned short sA[2][64 * 32];    // linear, no pad (global_load_lds)
    __shared__ unsigned short sB[2][128 * 32];
    const int tid = threadIdx.x;
    const int wave = tid >> 6, lane = tid & 63;
    const int wm = (wave >> 1) * 32, wn = (wave & 1) * 64;
    const int bm = blockIdx.x * 64, bn = blockIdx.y * 128;
    const int fr = lane & 15, fg = lane >> 4;

    const int srow = lane >> 2, schk = (lane & 3) * 8;
    const unsigned short* Ab  = A  + (size_t)(bm + wave * 16 + srow) * K + schk;
    const unsigned short* Bb0 = Bm + (size_t)(bn + wave * 32 + srow) * K + schk;
    const unsigned short* Bb1 = Bb0 + (size_t)16 * K;
    const int aw = (wave * 16) * 32, bw0 = (wave * 32) * 32, bw1 = (wave * 32 + 16) * 32;

    f32x4 acc[2][4] = {};
    const int nt = K >> 5;

    // prologue: stage tile 0
    gload_lds16(Ab, &sA[0][aw]);
    gload_lds16(Bb0, &sB[0][bw0]);
    gload_lds16(Bb1, &sB[0][bw1]);
    __syncthreads();

    int cur = 0;
    for (int t = 0; t < nt; ++t) {
        if (t + 1 < nt) {                 // issue next-tile loads; they fly under MFMA
            int kt = (t + 1) << 5;
            gload_lds16(Ab + kt, &sA[cur ^ 1][aw]);
            gload_lds16(Bb0 + kt, &sB[cur ^ 1][bw0]);
            gload_lds16(Bb1 + kt, &sB[cur ^ 1][bw1]);
        }
        short8 af[2], bf[4];
        #pragma unroll
        for (int mr = 0; mr < 2; ++mr) af[mr] = *(const short8*)&sA[cur][(wm + mr * 16 + fr) * 32 + fg * 8];
        #pragma unroll
        for (int nr = 0; nr < 4; ++nr) bf[nr] = *(const short8*)&sB[cur][(wn + nr * 16 + fr) * 32 + fg * 8];
        #pragma unroll
        for (int mr = 0; mr < 2; ++mr)
            #pragma unroll
            for (int nr = 0; nr < 4; ++nr)
                acc[mr][nr] = MFMA(af[mr], bf[nr], acc[mr][nr]);
        __syncthreads();                  // drains vmcnt (next tile landed) + lgkm
        cur ^= 1;
    }

    #pragma unroll
    for (int mr = 0; mr < 2; ++mr)
        #pragma unroll
        for (int nr = 0; nr < 4; ++nr)
            #pragma unroll
            for (int j = 0; j < 4; ++j) {
                int m = bm + wm + mr * 16 + fg * 4 + j;
                int n = bn + wn + nr * 16 + fr;
                float v = acc[mr][nr][j] + bias[n];
                if (EMODE == 0) {
                    Cf[(size_t)m * N + n] = v;
                } else if (EMODE == 1) {
                    int b = m >> 10, s = m & 1023, h = n >> 6, dc = n & 63;
                    Cb[(((size_t)(b * 16 + h)) * 1024 + s) * 64 + dc] = f2b(v);
                } else {
                    int b = m >> 10, s = m & 1023, h = n >> 6, dc = n & 63;
                    Cb[(((size_t)(b * 16 + h)) * 64 + dc) * 1024 + s] = f2b(v);
                }
            }
}

// ---------------- fused forget-attention ----------------
// grid (64,64) remapped: each XCD owns 8 complete heads. One block: 16 q-rows.
// Score strip in bf16 -> 35.4 KB LDS -> 4 blocks/CU. PV runs on unnormalized e2,
// 1/sum folded into the epilogue (linearity).
__global__ __launch_bounds__(256) void attn_fused(
    const unsigned short* __restrict__ Qh,   // [BH,S,64] bf16
    const unsigned short* __restrict__ Kh,   // [BH,S,64] bf16
    const unsigned short* __restrict__ Vt,   // [BH,64,S] bf16
    const float* __restrict__ gammas,        // [16]
    float* __restrict__ attn_out,            // [BH,S,S] f32
    unsigned short* __restrict__ ctx)        // [B*S,1024] bf16
{
    extern __shared__ char smem[];
    const int RS = 1032;                     // bf16 row stride; RS/2=516 == 4 mod 32 -> <=2-way
    unsigned short* s_s = (unsigned short*)smem;                       // [16][1032] s -> e2
    unsigned short* s_q = (unsigned short*)(smem + 16 * RS * 2);       // [16][72]
    float* s_inv = (float*)(smem + 16 * RS * 2 + 16 * 72 * 2);         // [16]
    const int S = 1024;

    int gid = blockIdx.y * gridDim.x + blockIdx.x;     // 0..4095
    int jj = gid >> 3;
    const int bh = (gid & 7) * 8 + (jj >> 6);
    const int qb = jj & 63;
    const int q0 = qb * 16;
    const int tid = threadIdx.x;
    const int wave = tid >> 6, lane = tid & 63, fr = lane & 15, fg = lane >> 4;

    // load Q tile [16][64]
    {
        int rr = tid >> 4, c4 = (tid & 15) * 4;
        *(uint2*)&s_q[rr * 72 + c4] = *(const uint2*)&Qh[((size_t)bh * S + q0 + rr) * 64 + c4];
    }
    __syncthreads();
    const int kmax = q0 + 15;

    // phase 1: scores = QK^T / 8 -> bf16 LDS strip (16-col tiles interleaved across waves)
    {
        short8 qf0 = *(const short8*)&s_q[fr * 72 + fg * 8];
        short8 qf1 = *(const short8*)&s_q[fr * 72 + 32 + fg * 8];
        const unsigned short* kbase = &Kh[(size_t)bh * S * 64];
        for (int nf = 0; nf < 16; ++nf) {
            int cb = (nf * 4 + wave) * 16;
            if (cb > kmax) break;   // wave-uniform causal skip
            const unsigned short* kb = kbase + (size_t)cb * 64;
            short8 kf0 = *(const short8*)&kb[fr * 64 + fg * 8];
            short8 kf1 = *(const short8*)&kb[fr * 64 + 32 + fg * 8];
            f32x4 a = {0.f, 0.f, 0.f, 0.f};
            a = MFMA(qf0, kf0, a);
            a = MFMA(qf1, kf1, a);
            #pragma unroll
            for (int j = 0; j < 4; ++j)
                s_s[(size_t)(fg * 4 + j) * RS + cb + fr] = f2b(a[j] * 0.125f);
        }
    }
    __syncthreads();

    // phase 2: fused softmax->cumsum->decay->exp2 on contiguous per-lane segments
    // (L = 4m, m odd -> conflict-free). One cross-lane scan per row. e2 stored bf16.
    {
        const int r = tid >> 4, sub = tid & 15;
        const int qr = q0 + r;
        unsigned short* srow = &s_s[(size_t)r * RS];
        const float ag = fabsf(gammas[bh & 15]);
        const int m = ((qb + 4) >> 2) | 1;     // ceil((qb+1)/4), forced odd
        const int L = 4 * m;
        const int base = sub * L;

        float seg = 0.f;
        for (int c = 0; c < m; ++c) {
            us4 s4 = *(const us4*)&srow[base + c * 4];
            #pragma unroll
            for (int j = 0; j < 4; ++j) {
                int kk = base + c * 4 + j;
                seg += (kk <= qr) ? __expf(b2f(s4[j])) : 0.f;
            }
        }
        float x = seg, t;
        t = __shfl_up(x, 1, 16); if (sub >= 1) x += t;
        t = __shfl_up(x, 2, 16); if (sub >= 2) x += t;
        t = __shfl_up(x, 4, 16); if (sub >= 4) x += t;
        t = __shfl_up(x, 8, 16); if (sub >= 8) x += t;
        const float T = __shfl(x, 15, 16);
        const float invT = 1.f / T;
        float run = x - seg;                   // exclusive prefix

        float ls2 = 0.f;
        for (int c = 0; c < m; ++c) {
            us4 s4 = *(const us4*)&srow[base + c * 4];
            us4 o;
            #pragma unroll
            for (int j = 0; j < 4; ++j) {
                int kk = base + c * 4 + j;
                bool act = kk <= qr;
                float s = b2f(s4[j]);
                float e = act ? __expf(s) : 0.f;
                run += e;
                float rem = fmaxf(T - run, 0.f) * invT;
                float dist = sqrtf(rem * (float)(qr - kk));
                float te = __expf(-ag * dist);
                float e2 = act ? __expf(s * te) : 0.f;
                o[j] = f2b(e2);
                ls2 += e2;
            }
            *(us4*)&srow[base + c * 4] = o;
        }
        us4 z = {0, 0, 0, 0};
        for (int c = 4 * L + sub; c < 256; c += 16)
            *(us4*)&srow[c * 4] = z;
        #pragma unroll
        for (int mm = 1; mm < 16; mm <<= 1) ls2 += __shfl_xor(ls2, mm, 16);
        if (sub == 0) s_inv[r] = 1.f / ls2;
    }
    __syncthreads();

    // phase 2b: attn write-out (barrier-free; overlaps phase 3's MFMA)
    for (int r2 = 0; r2 < 16; ++r2) {
        us4 e4 = *(const us4*)&s_s[(size_t)r2 * RS + tid * 4];
        float iv = s_inv[r2];
        f32x4 w = {b2f(e4[0]) * iv, b2f(e4[1]) * iv, b2f(e4[2]) * iv, b2f(e4[3]) * iv};
        __builtin_nontemporal_store(w,
            (f32x4*)(attn_out + ((size_t)bh * S + q0 + r2) * S + tid * 4));
    }

    // phase 3: ctx = (e2 @ V) * inv  (each wave: 16 d-columns)
    {
        const unsigned short* vb = &Vt[(size_t)bh * 64 * S];
        f32x4 acc = {0.f, 0.f, 0.f, 0.f};
        const int ktiles = (kmax + 32) >> 5;
        const unsigned short* prow = &s_s[(size_t)fr * RS];
        for (int kt = 0; kt < ktiles; ++kt) {
            short8 pa = *(const short8*)&prow[kt * 32 + fg * 8];
            short8 vf = *(const short8*)&vb[(size_t)(wave * 16 + fr) * S + kt * 32 + fg * 8];
            acc = MFMA(pa, vf, acc);
        }
        int b = bh >> 4, h = bh & 15;
        #pragma unroll
        for (int j = 0; j < 4; ++j) {
            float iv = s_inv[fg * 4 + j];
            ctx[((size_t)b * S + q0 + fg * 4 + j) * 1024 + h * 64 + wave * 16 + fr] = f2b(acc[j] * iv);
        }
    }
}

extern "C" void kernel_launch(void* const* d_in, const int* in_sizes, int n_in,
                              void* d_out, int out_size, void* d_ws, size_t ws_size,
                              hipStream_t stream) {
    const float* query  = (const float*)d_in[0];
    const float* key    = (const float*)d_in[1];
    const float* value  = (const float*)d_in[2];
    const float* Wq = (const float*)d_in[4];
    const float* bq = (const float*)d_in[5];
    const float* Wk = (const float*)d_in[6];
    const float* bk = (const float*)d_in[7];
    const float* Wv = (const float*)d_in[8];
    const float* bv = (const float*)d_in[9];
    const float* Wo = (const float*)d_in[10];
    const float* bo = (const float*)d_in[11];
    const float* gammas = (const float*)d_in[12];

    const int S = 1024, dmodel = 1024;
    const int M = 4 * S;
    const size_t MD = (size_t)M * dmodel;
    const size_t DD = (size_t)dmodel * dmodel;

    char* ws = (char*)d_ws;
    unsigned short* xq  = (unsigned short*)ws;            ws += MD * 2;
    unsigned short* xk  = (unsigned short*)ws;            ws += MD * 2;
    unsigned short* xv  = (unsigned short*)ws;            ws += MD * 2;
    unsigned short* wqb = (unsigned short*)ws;            ws += DD * 2;
    unsigned short* wkb = (unsigned short*)ws;            ws += DD * 2;
    unsigned short* wvb = (unsigned short*)ws;            ws += DD * 2;
    unsigned short* wob = (unsigned short*)ws;            ws += DD * 2;
    unsigned short* qh  = (unsigned short*)ws;            ws += MD * 2;
    unsigned short* kh  = (unsigned short*)ws;            ws += MD * 2;
    unsigned short* vt  = (unsigned short*)ws;            ws += MD * 2;
    unsigned short* ctx = (unsigned short*)ws;            ws += MD * 2;

    float* outp = (float*)d_out;
    float* attn_out = outp + MD;

    convk<<<dim3(4096, 3), 256, 0, stream>>>(query, key, value, nullptr, xq, xk, xv, nullptr, (int)MD);
    convk<<<dim3(1024, 4), 256, 0, stream>>>(Wq, Wk, Wv, Wo, wqb, wkb, wvb, wob, (int)DD);

    gemm_bt<1><<<dim3(64, 8), 256, 0, stream>>>(xq, wqb, bq, nullptr, qh, M, dmodel, dmodel);
    gemm_bt<1><<<dim3(64, 8), 256, 0, stream>>>(xk, wkb, bk, nullptr, kh, M, dmodel, dmodel);
    gemm_bt<2><<<dim3(64, 8), 256, 0, stream>>>(xv, wvb, bv, nullptr, vt, M, dmodel, dmodel);

    size_t lds = 16 * 1032 * 2 + 16 * 72 * 2 + 16 * 4;   // 35,392 B -> 4 blocks/CU
    attn_fused<<<dim3(64, 64), 256, lds, stream>>>(qh, kh, vt, gammas, attn_out, ctx);

    gemm_bt<0><<<dim3(64, 8), 256, 0, stream>>>(ctx, wob, bo, outp, nullptr, M, dmodel, dmodel);
}

// Round 6
// 186.110 us; speedup vs baseline: 3.6077x; 1.0478x over previous
//
#include <hip/hip_runtime.h>
#include <hip/hip_bf16.h>

typedef __attribute__((ext_vector_type(8))) short short8;
typedef __attribute__((ext_vector_type(4))) float f32x4;
typedef __attribute__((ext_vector_type(4))) unsigned short us4;

#define MFMA(a, b, c) __builtin_amdgcn_mfma_f32_16x16x32_bf16((a), (b), (c), 0, 0, 0)

static __device__ inline unsigned short f2b(float f) {
    __hip_bfloat16 h = __float2bfloat16(f);
    return *reinterpret_cast<unsigned short*>(&h);
}
static __device__ inline float b2f(unsigned short u) {
    unsigned int x = ((unsigned int)u) << 16;
    return __builtin_bit_cast(float, x);
}

// async global->LDS, 16B per lane. LDS dst must be wave-uniform base; HW adds lane*16.
static __device__ __forceinline__ void gload_lds16(const unsigned short* g, unsigned short* s) {
    __builtin_amdgcn_global_load_lds(
        (const __attribute__((address_space(1))) unsigned int*)(g),
        (__attribute__((address_space(3))) unsigned int*)(s),
        16, 0, 0);
}

// ---------------- f32 -> bf16 conversion, 7 tensors in one launch ----------------
__global__ __launch_bounds__(256) void convk(
    const float* __restrict__ i0, const float* __restrict__ i1, const float* __restrict__ i2,
    const float* __restrict__ i3, const float* __restrict__ i4, const float* __restrict__ i5,
    const float* __restrict__ i6,
    unsigned short* o0, unsigned short* o1, unsigned short* o2, unsigned short* o3,
    unsigned short* o4, unsigned short* o5, unsigned short* o6,
    int nbig, int nsmall)
{
    const float* in; unsigned short* out; int n;
    switch (blockIdx.y) {
        case 0: in = i0; out = o0; n = nbig; break;
        case 1: in = i1; out = o1; n = nbig; break;
        case 2: in = i2; out = o2; n = nbig; break;
        case 3: in = i3; out = o3; n = nsmall; break;
        case 4: in = i4; out = o4; n = nsmall; break;
        case 5: in = i5; out = o5; n = nsmall; break;
        default: in = i6; out = o6; n = nsmall; break;
    }
    int i = (blockIdx.x * 256 + threadIdx.x) * 4;
    if (i >= n) return;
    float4 v = *(const float4*)(in + i);
    us4 o;
    o[0] = f2b(v.x); o[1] = f2b(v.y); o[2] = f2b(v.z); o[3] = f2b(v.w);
    *(us4*)(out + i) = o;
}

// ---------------- bf16 GEMM body: 3-buffer, 2-deep prefetch, counted vmcnt ----------------
// BM=64, BN=128, BK=32, 256 threads (4 waves 2x2). C = A * B^T (+bias).
// emode 0: f32 row-major. 1: bf16 [B,H,S,dk]. 2: bf16 [B,H,dk,S].
__device__ __forceinline__ void gemm_body(
    const unsigned short* __restrict__ A,
    const unsigned short* __restrict__ Bm,
    const float* __restrict__ bias,
    float* __restrict__ Cf,
    unsigned short* __restrict__ Cb,
    int emode, int M, int N, int K, int bmx, int bnx,
    unsigned short (*sA)[64 * 32], unsigned short (*sB)[128 * 32])
{
    const int tid = threadIdx.x;
    const int wave = tid >> 6, lane = tid & 63;
    const int wm = (wave >> 1) * 32, wn = (wave & 1) * 64;
    const int bm = bmx * 64, bn = bnx * 128;
    const int fr = lane & 15, fg = lane >> 4;

    const int srow = lane >> 2, schk = (lane & 3) * 8;
    const unsigned short* Ab  = A  + (size_t)(bm + wave * 16 + srow) * K + schk;
    const unsigned short* Bb0 = Bm + (size_t)(bn + wave * 32 + srow) * K + schk;
    const unsigned short* Bb1 = Bb0 + (size_t)16 * K;
    const int aw = (wave * 16) * 32, bw0 = (wave * 32) * 32, bw1 = (wave * 32 + 16) * 32;

    f32x4 acc[2][4] = {};
    const int nt = K >> 5;

    // prologue: stage tiles 0 and 1 (6 loads in flight per wave)
    gload_lds16(Ab,       &sA[0][aw]);
    gload_lds16(Bb0,      &sB[0][bw0]);
    gload_lds16(Bb1,      &sB[0][bw1]);
    gload_lds16(Ab + 32,  &sA[1][aw]);
    gload_lds16(Bb0 + 32, &sB[1][bw0]);
    gload_lds16(Bb1 + 32, &sB[1][bw1]);

    for (int t = 0; t < nt; ++t) {
        const int cur = t % 3;
        // issue stage(t+2) into buf[(t+2)%3]; counted wait so tile t's loads (oldest 3) landed
        if (t + 2 < nt) {
            const int nxt = (t + 2) % 3;
            const int kt = (t + 2) << 5;
            gload_lds16(Ab + kt,  &sA[nxt][aw]);
            gload_lds16(Bb0 + kt, &sB[nxt][bw0]);
            gload_lds16(Bb1 + kt, &sB[nxt][bw1]);
            asm volatile("s_waitcnt vmcnt(6)" ::: "memory");
        } else if (t + 1 < nt) {
            asm volatile("s_waitcnt vmcnt(3)" ::: "memory");
        } else {
            asm volatile("s_waitcnt vmcnt(0)" ::: "memory");
        }
        __builtin_amdgcn_s_barrier();            // all waves' tile-t data in LDS
        __builtin_amdgcn_sched_barrier(0);       // pin ds_reads below the barrier

        short8 af[2], bf[4];
        #pragma unroll
        for (int mr = 0; mr < 2; ++mr) af[mr] = *(const short8*)&sA[cur][(wm + mr * 16 + fr) * 32 + fg * 8];
        #pragma unroll
        for (int nr = 0; nr < 4; ++nr) bf[nr] = *(const short8*)&sB[cur][(wn + nr * 16 + fr) * 32 + fg * 8];
        #pragma unroll
        for (int mr = 0; mr < 2; ++mr)
            #pragma unroll
            for (int nr = 0; nr < 4; ++nr)
                acc[mr][nr] = MFMA(af[mr], bf[nr], acc[mr][nr]);

        __builtin_amdgcn_s_barrier();            // reads of tile t done before stage(t+3) overwrites
        __builtin_amdgcn_sched_barrier(0);
    }

    #pragma unroll
    for (int mr = 0; mr < 2; ++mr)
        #pragma unroll
        for (int nr = 0; nr < 4; ++nr)
            #pragma unroll
            for (int j = 0; j < 4; ++j) {
                int m = bm + wm + mr * 16 + fg * 4 + j;
                int n = bn + wn + nr * 16 + fr;
                float v = acc[mr][nr][j] + bias[n];
                if (emode == 0) {
                    Cf[(size_t)m * N + n] = v;
                } else if (emode == 1) {
                    int b = m >> 10, s = m & 1023, h = n >> 6, dc = n & 63;
                    Cb[(((size_t)(b * 16 + h)) * 1024 + s) * 64 + dc] = f2b(v);
                } else {
                    int b = m >> 10, s = m & 1023, h = n >> 6, dc = n & 63;
                    Cb[(((size_t)(b * 16 + h)) * 64 + dc) * 1024 + s] = f2b(v);
                }
            }
}

// fused QKV projection: grid (64, 8, 3); z selects {q,k,v}
__global__ __launch_bounds__(256) void gemm_qkv(
    const unsigned short* __restrict__ xq, const unsigned short* __restrict__ xk,
    const unsigned short* __restrict__ xv,
    const unsigned short* __restrict__ wq, const unsigned short* __restrict__ wk,
    const unsigned short* __restrict__ wv,
    const float* __restrict__ bq, const float* __restrict__ bk, const float* __restrict__ bv,
    unsigned short* __restrict__ qh, unsigned short* __restrict__ kh,
    unsigned short* __restrict__ vt,
    int M, int N, int K)
{
    __shared__ unsigned short sA[3][64 * 32];
    __shared__ unsigned short sB[3][128 * 32];
    const int z = blockIdx.z;
    const unsigned short* A  = z == 0 ? xq : z == 1 ? xk : xv;
    const unsigned short* Bm = z == 0 ? wq : z == 1 ? wk : wv;
    const float* bias        = z == 0 ? bq : z == 1 ? bk : bv;
    unsigned short* Cb       = z == 0 ? qh : z == 1 ? kh : vt;
    gemm_body(A, Bm, bias, nullptr, Cb, z == 2 ? 2 : 1, M, N, K,
              blockIdx.x, blockIdx.y, sA, sB);
}

__global__ __launch_bounds__(256) void gemm_wo(
    const unsigned short* __restrict__ A, const unsigned short* __restrict__ Bm,
    const float* __restrict__ bias, float* __restrict__ Cf, int M, int N, int K)
{
    __shared__ unsigned short sA[3][64 * 32];
    __shared__ unsigned short sB[3][128 * 32];
    gemm_body(A, Bm, bias, Cf, nullptr, 0, M, N, K, blockIdx.x, blockIdx.y, sA, sB);
}

// ---------------- fused forget-attention (unchanged from R5) ----------------
__global__ __launch_bounds__(256) void attn_fused(
    const unsigned short* __restrict__ Qh,   // [BH,S,64] bf16
    const unsigned short* __restrict__ Kh,   // [BH,S,64] bf16
    const unsigned short* __restrict__ Vt,   // [BH,64,S] bf16
    const float* __restrict__ gammas,        // [16]
    float* __restrict__ attn_out,            // [BH,S,S] f32
    unsigned short* __restrict__ ctx)        // [B*S,1024] bf16
{
    extern __shared__ char smem[];
    const int RS = 1032;                     // bf16 row stride; RS/2=516 == 4 mod 32 -> <=2-way
    unsigned short* s_s = (unsigned short*)smem;                       // [16][1032] s -> e2
    unsigned short* s_q = (unsigned short*)(smem + 16 * RS * 2);       // [16][72]
    float* s_inv = (float*)(smem + 16 * RS * 2 + 16 * 72 * 2);         // [16]
    const int S = 1024;

    int gid = blockIdx.y * gridDim.x + blockIdx.x;     // 0..4095
    int jj = gid >> 3;
    const int bh = (gid & 7) * 8 + (jj >> 6);
    const int qb = jj & 63;
    const int q0 = qb * 16;
    const int tid = threadIdx.x;
    const int wave = tid >> 6, lane = tid & 63, fr = lane & 15, fg = lane >> 4;

    {
        int rr = tid >> 4, c4 = (tid & 15) * 4;
        *(uint2*)&s_q[rr * 72 + c4] = *(const uint2*)&Qh[((size_t)bh * S + q0 + rr) * 64 + c4];
    }
    __syncthreads();
    const int kmax = q0 + 15;

    // phase 1: scores = QK^T / 8 -> bf16 LDS strip (16-col tiles interleaved across waves)
    {
        short8 qf0 = *(const short8*)&s_q[fr * 72 + fg * 8];
        short8 qf1 = *(const short8*)&s_q[fr * 72 + 32 + fg * 8];
        const unsigned short* kbase = &Kh[(size_t)bh * S * 64];
        for (int nf = 0; nf < 16; ++nf) {
            int cb = (nf * 4 + wave) * 16;
            if (cb > kmax) break;   // wave-uniform causal skip
            const unsigned short* kb = kbase + (size_t)cb * 64;
            short8 kf0 = *(const short8*)&kb[fr * 64 + fg * 8];
            short8 kf1 = *(const short8*)&kb[fr * 64 + 32 + fg * 8];
            f32x4 a = {0.f, 0.f, 0.f, 0.f};
            a = MFMA(qf0, kf0, a);
            a = MFMA(qf1, kf1, a);
            #pragma unroll
            for (int j = 0; j < 4; ++j)
                s_s[(size_t)(fg * 4 + j) * RS + cb + fr] = f2b(a[j] * 0.125f);
        }
    }
    __syncthreads();

    // phase 2: fused softmax->cumsum->decay->exp2 on contiguous per-lane segments
    {
        const int r = tid >> 4, sub = tid & 15;
        const int qr = q0 + r;
        unsigned short* srow = &s_s[(size_t)r * RS];
        const float ag = fabsf(gammas[bh & 15]);
        const int m = ((qb + 4) >> 2) | 1;     // ceil((qb+1)/4), forced odd
        const int L = 4 * m;
        const int base = sub * L;

        float seg = 0.f;
        for (int c = 0; c < m; ++c) {
            us4 s4 = *(const us4*)&srow[base + c * 4];
            #pragma unroll
            for (int j = 0; j < 4; ++j) {
                int kk = base + c * 4 + j;
                seg += (kk <= qr) ? __expf(b2f(s4[j])) : 0.f;
            }
        }
        float x = seg, t;
        t = __shfl_up(x, 1, 16); if (sub >= 1) x += t;
        t = __shfl_up(x, 2, 16); if (sub >= 2) x += t;
        t = __shfl_up(x, 4, 16); if (sub >= 4) x += t;
        t = __shfl_up(x, 8, 16); if (sub >= 8) x += t;
        const float T = __shfl(x, 15, 16);
        const float invT = 1.f / T;
        float run = x - seg;                   // exclusive prefix

        float ls2 = 0.f;
        for (int c = 0; c < m; ++c) {
            us4 s4 = *(const us4*)&srow[base + c * 4];
            us4 o;
            #pragma unroll
            for (int j = 0; j < 4; ++j) {
                int kk = base + c * 4 + j;
                bool act = kk <= qr;
                float s = b2f(s4[j]);
                float e = act ? __expf(s) : 0.f;
                run += e;
                float rem = fmaxf(T - run, 0.f) * invT;
                float dist = sqrtf(rem * (float)(qr - kk));
                float te = __expf(-ag * dist);
                float e2 = act ? __expf(s * te) : 0.f;
                o[j] = f2b(e2);
                ls2 += e2;
            }
            *(us4*)&srow[base + c * 4] = o;
        }
        us4 z = {0, 0, 0, 0};
        for (int c = 4 * L + sub; c < 256; c += 16)
            *(us4*)&srow[c * 4] = z;
        #pragma unroll
        for (int mm = 1; mm < 16; mm <<= 1) ls2 += __shfl_xor(ls2, mm, 16);
        if (sub == 0) s_inv[r] = 1.f / ls2;
    }
    __syncthreads();

    // phase 2b: attn write-out (barrier-free; overlaps phase 3's MFMA)
    for (int r2 = 0; r2 < 16; ++r2) {
        us4 e4 = *(const us4*)&s_s[(size_t)r2 * RS + tid * 4];
        float iv = s_inv[r2];
        f32x4 w = {b2f(e4[0]) * iv, b2f(e4[1]) * iv, b2f(e4[2]) * iv, b2f(e4[3]) * iv};
        __builtin_nontemporal_store(w,
            (f32x4*)(attn_out + ((size_t)bh * S + q0 + r2) * S + tid * 4));
    }

    // phase 3: ctx = (e2 @ V) * inv  (each wave: 16 d-columns)
    {
        const unsigned short* vb = &Vt[(size_t)bh * 64 * S];
        f32x4 acc = {0.f, 0.f, 0.f, 0.f};
        const int ktiles = (kmax + 32) >> 5;
        const unsigned short* prow = &s_s[(size_t)fr * RS];
        for (int kt = 0; kt < ktiles; ++kt) {
            short8 pa = *(const short8*)&prow[kt * 32 + fg * 8];
            short8 vf = *(const short8*)&vb[(size_t)(wave * 16 + fr) * S + kt * 32 + fg * 8];
            acc = MFMA(pa, vf, acc);
        }
        int b = bh >> 4, h = bh & 15;
        #pragma unroll
        for (int j = 0; j < 4; ++j) {
            float iv = s_inv[fg * 4 + j];
            ctx[((size_t)b * S + q0 + fg * 4 + j) * 1024 + h * 64 + wave * 16 + fr] = f2b(acc[j] * iv);
        }
    }
}

extern "C" void kernel_launch(void* const* d_in, const int* in_sizes, int n_in,
                              void* d_out, int out_size, void* d_ws, size_t ws_size,
                              hipStream_t stream) {
    const float* query  = (const float*)d_in[0];
    const float* key    = (const float*)d_in[1];
    const float* value  = (const float*)d_in[2];
    const float* Wq = (const float*)d_in[4];
    const float* bq = (const float*)d_in[5];
    const float* Wk = (const float*)d_in[6];
    const float* bk = (const float*)d_in[7];
    const float* Wv = (const float*)d_in[8];
    const float* bv = (const float*)d_in[9];
    const float* Wo = (const float*)d_in[10];
    const float* bo = (const float*)d_in[11];
    const float* gammas = (const float*)d_in[12];

    const int S = 1024, dmodel = 1024;
    const int M = 4 * S;
    const size_t MD = (size_t)M * dmodel;
    const size_t DD = (size_t)dmodel * dmodel;

    char* ws = (char*)d_ws;
    unsigned short* xq  = (unsigned short*)ws;            ws += MD * 2;
    unsigned short* xk  = (unsigned short*)ws;            ws += MD * 2;
    unsigned short* xv  = (unsigned short*)ws;            ws += MD * 2;
    unsigned short* wqb = (unsigned short*)ws;            ws += DD * 2;
    unsigned short* wkb = (unsigned short*)ws;            ws += DD * 2;
    unsigned short* wvb = (unsigned short*)ws;            ws += DD * 2;
    unsigned short* wob = (unsigned short*)ws;            ws += DD * 2;
    unsigned short* qh  = (unsigned short*)ws;            ws += MD * 2;
    unsigned short* kh  = (unsigned short*)ws;            ws += MD * 2;
    unsigned short* vt  = (unsigned short*)ws;            ws += MD * 2;
    unsigned short* ctx = (unsigned short*)ws;            ws += MD * 2;

    float* outp = (float*)d_out;
    float* attn_out = outp + MD;

    // 1) all f32->bf16 conversions in one launch
    convk<<<dim3(4096, 7), 256, 0, stream>>>(
        query, key, value, Wq, Wk, Wv, Wo,
        xq, xk, xv, wqb, wkb, wvb, wob, (int)MD, (int)DD);

    // 2) fused QKV projections (one launch, z-indexed)
    gemm_qkv<<<dim3(64, 8, 3), 256, 0, stream>>>(
        xq, xk, xv, wqb, wkb, wvb, bq, bk, bv, qh, kh, vt, M, dmodel, dmodel);

    // 3) fused forget-attention
    size_t lds = 16 * 1032 * 2 + 16 * 72 * 2 + 16 * 4;   // 35,392 B -> 4 blocks/CU
    attn_fused<<<dim3(64, 64), 256, lds, stream>>>(qh, kh, vt, gammas, attn_out, ctx);

    // 4) output projection
    gemm_wo<<<dim3(64, 8), 256, 0, stream>>>(ctx, wob, bo, outp, M, dmodel, dmodel);
}

// Round 8
// 183.875 us; speedup vs baseline: 3.6515x; 1.0122x over previous
//
#include <hip/hip_runtime.h>
#include <hip/hip_bf16.h>

typedef __attribute__((ext_vector_type(8))) short short8;
typedef __attribute__((ext_vector_type(4))) float f32x4;
typedef __attribute__((ext_vector_type(4))) unsigned short us4;

#define MFMA(a, b, c) __builtin_amdgcn_mfma_f32_16x16x32_bf16((a), (b), (c), 0, 0, 0)

static __device__ inline unsigned short f2b(float f) {
    __hip_bfloat16 h = __float2bfloat16(f);
    return *reinterpret_cast<unsigned short*>(&h);
}
static __device__ inline float b2f(unsigned short u) {
    unsigned int x = ((unsigned int)u) << 16;
    return __builtin_bit_cast(float, x);
}

// async global->LDS, 16B per lane. LDS dst must be wave-uniform base; HW adds lane*16.
static __device__ __forceinline__ void gload_lds16(const unsigned short* g, unsigned short* s) {
    __builtin_amdgcn_global_load_lds(
        (const __attribute__((address_space(1))) unsigned int*)(g),
        (__attribute__((address_space(3))) unsigned int*)(s),
        16, 0, 0);
}
#define WAITV(N) asm volatile("s_waitcnt vmcnt(" #N ")" ::: "memory")
#define WAITL    asm volatile("s_waitcnt lgkmcnt(0)" ::: "memory")
#define SBAR     __builtin_amdgcn_s_barrier()
#define SCHED0   __builtin_amdgcn_sched_barrier(0)

// ---------------- f32 -> bf16 conversion (weights only) ----------------
__global__ __launch_bounds__(256) void convk(
    const float* __restrict__ i0, const float* __restrict__ i1,
    const float* __restrict__ i2, const float* __restrict__ i3,
    unsigned short* o0, unsigned short* o1, unsigned short* o2, unsigned short* o3, int n)
{
    const float* in; unsigned short* out;
    switch (blockIdx.y) {
        case 0: in = i0; out = o0; break;
        case 1: in = i1; out = o1; break;
        case 2: in = i2; out = o2; break;
        default: in = i3; out = o3; break;
    }
    int i = (blockIdx.x * 256 + threadIdx.x) * 4;
    if (i >= n) return;
    float4 v = *(const float4*)(in + i);
    us4 o;
    o[0] = f2b(v.x); o[1] = f2b(v.y); o[2] = f2b(v.z); o[3] = f2b(v.w);
    *(us4*)(out + i) = o;
}

// ======== fused-convert QKV GEMM: C = f32A * bf16B^T + bias ========
// BM=64, BN=128, BK=64, 256 thr (4 waves 2x2, 16 MFMA/K-step/wave).
// A read as f32 (SINGLE reg set rA), converted in-reg, ds_write staged; B via
// global_load_lds. 3 LDS bufs, counted vmcnt. Queue invariant at loop head:
// {B(t):4, A(t+1):4, B(t+1):4} per wave; A issued BEFORE B each iter (SCHED0-pinned).
__global__ __launch_bounds__(256) void gemm_qkv(
    const float* __restrict__ Aq, const float* __restrict__ Ak, const float* __restrict__ Av,
    const unsigned short* __restrict__ wq, const unsigned short* __restrict__ wk,
    const unsigned short* __restrict__ wv,
    const float* __restrict__ bq, const float* __restrict__ bk, const float* __restrict__ bv,
    unsigned short* __restrict__ qh, unsigned short* __restrict__ kh,
    unsigned short* __restrict__ vt,
    int M, int N, int K)
{
    __shared__ unsigned short sA[3][2 * 64 * 32];    // [buf][ks*64+row][32]
    __shared__ unsigned short sB[3][2 * 128 * 32];
    const int z = blockIdx.z;
    const float* A           = z == 0 ? Aq : z == 1 ? Ak : Av;
    const unsigned short* Bm = z == 0 ? wq : z == 1 ? wk : wv;
    const float* bias        = z == 0 ? bq : z == 1 ? bk : bv;
    unsigned short* Cb       = z == 0 ? qh : z == 1 ? kh : vt;
    const int emode          = z == 2 ? 2 : 1;

    const int tid = threadIdx.x;
    const int wave = tid >> 6, lane = tid & 63;
    const int wm = (wave >> 1) * 32, wn = (wave & 1) * 64;
    const int bm = blockIdx.x * 64, bn = blockIdx.y * 128;
    const int fr = lane & 15, fg = lane >> 4;

    // A staging: thread -> row=tid>>2, 16 f32 at col (tid&3)*16
    const int ar = tid >> 2, ac = (tid & 3) * 16;
    const float* Ag = A + (size_t)(bm + ar) * K + ac;
    const int aks = ac >> 5, acol = ac & 31;
    // B staging: per wave 4 gloads covering rows wave*32..+31 x two 32-col k-slices
    const int brow = lane >> 2, bchk = (lane & 3) * 8;
    const unsigned short* Bg = Bm + (size_t)(bn + wave * 32 + brow) * K + bchk;

    f32x4 acc[2][4] = {};
    const int nt = K >> 6;                            // 16

    float4 rA[4];
    #define LOAD_A(t)  { const float* p = Ag + ((t) << 6); \
        rA[0] = *(const float4*)(p); rA[1] = *(const float4*)(p + 4); \
        rA[2] = *(const float4*)(p + 8); rA[3] = *(const float4*)(p + 12); }
    #define GLOAD_B(buf, t) { const unsigned short* p = Bg + ((t) << 6); \
        gload_lds16(p,               &sB[buf][(0 * 128 + wave * 32 + 0 ) * 32]); \
        gload_lds16(p + 16 * K,      &sB[buf][(0 * 128 + wave * 32 + 16) * 32]); \
        gload_lds16(p + 32,          &sB[buf][(1 * 128 + wave * 32 + 0 ) * 32]); \
        gload_lds16(p + 16 * K + 32, &sB[buf][(1 * 128 + wave * 32 + 16) * 32]); }
    #define WRITE_A(buf) { \
        unsigned short* d = &sA[buf][(aks * 64 + ar) * 32 + acol]; \
        us4 w0, w1; \
        w0[0] = f2b(rA[0].x); w0[1] = f2b(rA[0].y); w0[2] = f2b(rA[0].z); w0[3] = f2b(rA[0].w); \
        w1[0] = f2b(rA[1].x); w1[1] = f2b(rA[1].y); w1[2] = f2b(rA[1].z); w1[3] = f2b(rA[1].w); \
        *(us4*)(d) = w0; *(us4*)(d + 4) = w1; \
        w0[0] = f2b(rA[2].x); w0[1] = f2b(rA[2].y); w0[2] = f2b(rA[2].z); w0[3] = f2b(rA[2].w); \
        w1[0] = f2b(rA[3].x); w1[1] = f2b(rA[3].y); w1[2] = f2b(rA[3].z); w1[3] = f2b(rA[3].w); \
        *(us4*)(d + 8) = w0; *(us4*)(d + 12) = w1; }

    // prologue: A0 -> regs -> LDS buf0; B0 -> buf0; A1 -> regs; B1 -> buf1
    LOAD_A(0);
    SCHED0;
    GLOAD_B(0, 0);                 // queue: {A0:4, B0:4}
    WAITV(4);                      // A0 landed (B0 outstanding)
    WRITE_A(0);
    LOAD_A(1);
    SCHED0;
    GLOAD_B(1, 1);                 // queue: {B0:4, A1:4, B1:4}  == invariant

    for (int t = 0; t < nt; ++t) {
        const int cur = t % 3;
        if (t + 1 < nt) { WAITV(4); } else { WAITV(0); }   // retire B(t) + A(t+1)
        if (t + 1 < nt) { WRITE_A((t + 1) % 3); }          // A(t+1) regs -> LDS
        if (t + 2 < nt) {
            LOAD_A(t + 2);                                 // A before B (queue order!)
            SCHED0;
            GLOAD_B((t + 2) % 3, t + 2);
        }
        WAITL;                      // own ds_writes done
        SBAR; SCHED0;               // tile t fully staged across waves

        short8 af[2][2], bf[4][2];
        #pragma unroll
        for (int ks = 0; ks < 2; ++ks) {
            #pragma unroll
            for (int mr = 0; mr < 2; ++mr)
                af[mr][ks] = *(const short8*)&sA[cur][(ks * 64 + wm + mr * 16 + fr) * 32 + fg * 8];
            #pragma unroll
            for (int nr = 0; nr < 4; ++nr)
                bf[nr][ks] = *(const short8*)&sB[cur][(ks * 128 + wn + nr * 16 + fr) * 32 + fg * 8];
        }
        #pragma unroll
        for (int ks = 0; ks < 2; ++ks)
            #pragma unroll
            for (int mr = 0; mr < 2; ++mr)
                #pragma unroll
                for (int nr = 0; nr < 4; ++nr)
                    acc[mr][nr] = MFMA(af[mr][ks], bf[nr][ks], acc[mr][nr]);

        SCHED0; SBAR;               // reads of tile t done before its buf re-staged
    }

    #pragma unroll
    for (int mr = 0; mr < 2; ++mr)
        #pragma unroll
        for (int nr = 0; nr < 4; ++nr)
            #pragma unroll
            for (int j = 0; j < 4; ++j) {
                int m = bm + wm + mr * 16 + fg * 4 + j;
                int n = bn + wn + nr * 16 + fr;
                float v = acc[mr][nr][j] + bias[n];
                int b = m >> 10, s = m & 1023, h = n >> 6, dc = n & 63;
                if (emode == 1)
                    Cb[(((size_t)(b * 16 + h)) * 1024 + s) * 64 + dc] = f2b(v);
                else
                    Cb[(((size_t)(b * 16 + h)) * 64 + dc) * 1024 + s] = f2b(v);
            }
    #undef LOAD_A
    #undef GLOAD_B
    #undef WRITE_A
}

// ======== Wo GEMM: bf16 A (ctx), all-gload staging, BK=64, 3 bufs ========
// 6 gloads/iter; exact ladder: steady WAITV(12) retires tile t; tail 6 -> 0.
__global__ __launch_bounds__(256) void gemm_wo(
    const unsigned short* __restrict__ A, const unsigned short* __restrict__ Bm,
    const float* __restrict__ bias, float* __restrict__ Cf, int M, int N, int K)
{
    __shared__ unsigned short sA[3][2 * 64 * 32];
    __shared__ unsigned short sB[3][2 * 128 * 32];
    const int tid = threadIdx.x;
    const int wave = tid >> 6, lane = tid & 63;
    const int wm = (wave >> 1) * 32, wn = (wave & 1) * 64;
    const int bm = blockIdx.x * 64, bn = blockIdx.y * 128;
    const int fr = lane & 15, fg = lane >> 4;

    const int srow = lane >> 2, schk = (lane & 3) * 8;
    const unsigned short* Ag = A + (size_t)(bm + wave * 16 + srow) * K + schk;
    const unsigned short* Bg = Bm + (size_t)(bn + wave * 32 + srow) * K + schk;

    #define STAGE(buf, t) { const unsigned short* ap = Ag + ((t) << 6); \
        gload_lds16(ap,      &sA[buf][(0 * 64 + wave * 16) * 32]); \
        gload_lds16(ap + 32, &sA[buf][(1 * 64 + wave * 16) * 32]); \
        const unsigned short* bp = Bg + ((t) << 6); \
        gload_lds16(bp,               &sB[buf][(0 * 128 + wave * 32 + 0 ) * 32]); \
        gload_lds16(bp + 16 * K,      &sB[buf][(0 * 128 + wave * 32 + 16) * 32]); \
        gload_lds16(bp + 32,          &sB[buf][(1 * 128 + wave * 32 + 0 ) * 32]); \
        gload_lds16(bp + 16 * K + 32, &sB[buf][(1 * 128 + wave * 32 + 16) * 32]); }

    f32x4 acc[2][4] = {};
    const int nt = K >> 6;

    STAGE(0, 0); STAGE(1, 1);       // queue: {t0:6, t1:6}
    for (int t = 0; t < nt; ++t) {
        const int cur = t % 3;
        if (t + 2 < nt)      { STAGE((t + 2) % 3, t + 2); WAITV(12); }  // retire tile t
        else if (t + 1 < nt) { WAITV(6); }                              // t == nt-2
        else                 { WAITV(0); }                              // t == nt-1
        SBAR; SCHED0;

        short8 af[2][2], bf[4][2];
        #pragma unroll
        for (int ks = 0; ks < 2; ++ks) {
            #pragma unroll
            for (int mr = 0; mr < 2; ++mr)
                af[mr][ks] = *(const short8*)&sA[cur][(ks * 64 + wm + mr * 16 + fr) * 32 + fg * 8];
            #pragma unroll
            for (int nr = 0; nr < 4; ++nr)
                bf[nr][ks] = *(const short8*)&sB[cur][(ks * 128 + wn + nr * 16 + fr) * 32 + fg * 8];
        }
        #pragma unroll
        for (int ks = 0; ks < 2; ++ks)
            #pragma unroll
            for (int mr = 0; mr < 2; ++mr)
                #pragma unroll
                for (int nr = 0; nr < 4; ++nr)
                    acc[mr][nr] = MFMA(af[mr][ks], bf[nr][ks], acc[mr][nr]);

        SCHED0; SBAR;
    }
    #undef STAGE

    #pragma unroll
    for (int mr = 0; mr < 2; ++mr)
        #pragma unroll
        for (int nr = 0; nr < 4; ++nr)
            #pragma unroll
            for (int j = 0; j < 4; ++j) {
                int m = bm + wm + mr * 16 + fg * 4 + j;
                int n = bn + wn + nr * 16 + fr;
                Cf[(size_t)m * N + n] = acc[mr][nr][j] + bias[n];
            }
}

// ---------------- fused forget-attention (unchanged from R6) ----------------
__global__ __launch_bounds__(256) void attn_fused(
    const unsigned short* __restrict__ Qh,   // [BH,S,64] bf16
    const unsigned short* __restrict__ Kh,   // [BH,S,64] bf16
    const unsigned short* __restrict__ Vt,   // [BH,64,S] bf16
    const float* __restrict__ gammas,        // [16]
    float* __restrict__ attn_out,            // [BH,S,S] f32
    unsigned short* __restrict__ ctx)        // [B*S,1024] bf16
{
    extern __shared__ char smem[];
    const int RS = 1032;                     // bf16 row stride
    unsigned short* s_s = (unsigned short*)smem;                       // [16][1032] s -> e2
    unsigned short* s_q = (unsigned short*)(smem + 16 * RS * 2);       // [16][72]
    float* s_inv = (float*)(smem + 16 * RS * 2 + 16 * 72 * 2);         // [16]
    const int S = 1024;

    int gid = blockIdx.y * gridDim.x + blockIdx.x;     // 0..4095
    int jj = gid >> 3;
    const int bh = (gid & 7) * 8 + (jj >> 6);
    const int qb = jj & 63;
    const int q0 = qb * 16;
    const int tid = threadIdx.x;
    const int wave = tid >> 6, lane = tid & 63, fr = lane & 15, fg = lane >> 4;

    {
        int rr = tid >> 4, c4 = (tid & 15) * 4;
        *(uint2*)&s_q[rr * 72 + c4] = *(const uint2*)&Qh[((size_t)bh * S + q0 + rr) * 64 + c4];
    }
    __syncthreads();
    const int kmax = q0 + 15;

    // phase 1: scores = QK^T / 8 -> bf16 LDS strip (16-col tiles interleaved across waves)
    {
        short8 qf0 = *(const short8*)&s_q[fr * 72 + fg * 8];
        short8 qf1 = *(const short8*)&s_q[fr * 72 + 32 + fg * 8];
        const unsigned short* kbase = &Kh[(size_t)bh * S * 64];
        for (int nf = 0; nf < 16; ++nf) {
            int cb = (nf * 4 + wave) * 16;
            if (cb > kmax) break;
            const unsigned short* kb = kbase + (size_t)cb * 64;
            short8 kf0 = *(const short8*)&kb[fr * 64 + fg * 8];
            short8 kf1 = *(const short8*)&kb[fr * 64 + 32 + fg * 8];
            f32x4 a = {0.f, 0.f, 0.f, 0.f};
            a = MFMA(qf0, kf0, a);
            a = MFMA(qf1, kf1, a);
            #pragma unroll
            for (int j = 0; j < 4; ++j)
                s_s[(size_t)(fg * 4 + j) * RS + cb + fr] = f2b(a[j] * 0.125f);
        }
    }
    __syncthreads();

    // phase 2: fused softmax->cumsum->decay->exp2 on contiguous per-lane segments
    {
        const int r = tid >> 4, sub = tid & 15;
        const int qr = q0 + r;
        unsigned short* srow = &s_s[(size_t)r * RS];
        const float ag = fabsf(gammas[bh & 15]);
        const int m = ((qb + 4) >> 2) | 1;     // ceil((qb+1)/4), forced odd
        const int L = 4 * m;
        const int base = sub * L;

        float seg = 0.f;
        for (int c = 0; c < m; ++c) {
            us4 s4 = *(const us4*)&srow[base + c * 4];
            #pragma unroll
            for (int j = 0; j < 4; ++j) {
                int kk = base + c * 4 + j;
                seg += (kk <= qr) ? __expf(b2f(s4[j])) : 0.f;
            }
        }
        float x = seg, t;
        t = __shfl_up(x, 1, 16); if (sub >= 1) x += t;
        t = __shfl_up(x, 2, 16); if (sub >= 2) x += t;
        t = __shfl_up(x, 4, 16); if (sub >= 4) x += t;
        t = __shfl_up(x, 8, 16); if (sub >= 8) x += t;
        const float T = __shfl(x, 15, 16);
        const float invT = 1.f / T;
        float run = x - seg;

        float ls2 = 0.f;
        for (int c = 0; c < m; ++c) {
            us4 s4 = *(const us4*)&srow[base + c * 4];
            us4 o;
            #pragma unroll
            for (int j = 0; j < 4; ++j) {
                int kk = base + c * 4 + j;
                bool act = kk <= qr;
                float s = b2f(s4[j]);
                float e = act ? __expf(s) : 0.f;
                run += e;
                float rem = fmaxf(T - run, 0.f) * invT;
                float dist = sqrtf(rem * (float)(qr - kk));
                float te = __expf(-ag * dist);
                float e2 = act ? __expf(s * te) : 0.f;
                o[j] = f2b(e2);
                ls2 += e2;
            }
            *(us4*)&srow[base + c * 4] = o;
        }
        us4 z = {0, 0, 0, 0};
        for (int c = 4 * L + sub; c < 256; c += 16)
            *(us4*)&srow[c * 4] = z;
        #pragma unroll
        for (int mm = 1; mm < 16; mm <<= 1) ls2 += __shfl_xor(ls2, mm, 16);
        if (sub == 0) s_inv[r] = 1.f / ls2;
    }
    __syncthreads();

    // phase 2b: attn write-out (barrier-free; overlaps phase 3's MFMA)
    for (int r2 = 0; r2 < 16; ++r2) {
        us4 e4 = *(const us4*)&s_s[(size_t)r2 * RS + tid * 4];
        float iv = s_inv[r2];
        f32x4 w = {b2f(e4[0]) * iv, b2f(e4[1]) * iv, b2f(e4[2]) * iv, b2f(e4[3]) * iv};
        __builtin_nontemporal_store(w,
            (f32x4*)(attn_out + ((size_t)bh * S + q0 + r2) * S + tid * 4));
    }

    // phase 3: ctx = (e2 @ V) * inv  (each wave: 16 d-columns)
    {
        const unsigned short* vb = &Vt[(size_t)bh * 64 * S];
        f32x4 acc = {0.f, 0.f, 0.f, 0.f};
        const int ktiles = (kmax + 32) >> 5;
        const unsigned short* prow = &s_s[(size_t)fr * RS];
        for (int kt = 0; kt < ktiles; ++kt) {
            short8 pa = *(const short8*)&prow[kt * 32 + fg * 8];
            short8 vf = *(const short8*)&vb[(size_t)(wave * 16 + fr) * S + kt * 32 + fg * 8];
            acc = MFMA(pa, vf, acc);
        }
        int b = bh >> 4, h = bh & 15;
        #pragma unroll
        for (int j = 0; j < 4; ++j) {
            float iv = s_inv[fg * 4 + j];
            ctx[((size_t)b * S + q0 + fg * 4 + j) * 1024 + h * 64 + wave * 16 + fr] = f2b(acc[j] * iv);
        }
    }
}

extern "C" void kernel_launch(void* const* d_in, const int* in_sizes, int n_in,
                              void* d_out, int out_size, void* d_ws, size_t ws_size,
                              hipStream_t stream) {
    const float* query  = (const float*)d_in[0];
    const float* key    = (const float*)d_in[1];
    const float* value  = (const float*)d_in[2];
    const float* Wq = (const float*)d_in[4];
    const float* bq = (const float*)d_in[5];
    const float* Wk = (const float*)d_in[6];
    const float* bk = (const float*)d_in[7];
    const float* Wv = (const float*)d_in[8];
    const float* bv = (const float*)d_in[9];
    const float* Wo = (const float*)d_in[10];
    const float* bo = (const float*)d_in[11];
    const float* gammas = (const float*)d_in[12];

    const int S = 1024, dmodel = 1024;
    const int M = 4 * S;
    const size_t MD = (size_t)M * dmodel;
    const size_t DD = (size_t)dmodel * dmodel;

    char* ws = (char*)d_ws;
    unsigned short* wqb = (unsigned short*)ws;            ws += DD * 2;
    unsigned short* wkb = (unsigned short*)ws;            ws += DD * 2;
    unsigned short* wvb = (unsigned short*)ws;            ws += DD * 2;
    unsigned short* wob = (unsigned short*)ws;            ws += DD * 2;
    unsigned short* qh  = (unsigned short*)ws;            ws += MD * 2;
    unsigned short* kh  = (unsigned short*)ws;            ws += MD * 2;
    unsigned short* vt  = (unsigned short*)ws;            ws += MD * 2;
    unsigned short* ctx = (unsigned short*)ws;            ws += MD * 2;

    float* outp = (float*)d_out;
    float* attn_out = outp + MD;

    // 1) weight conversions only (x converts inside gemm_qkv's A-staging)
    convk<<<dim3(1024, 4), 256, 0, stream>>>(Wq, Wk, Wv, Wo, wqb, wkb, wvb, wob, (int)DD);

    // 2) fused-convert QKV projections
    gemm_qkv<<<dim3(64, 8, 3), 256, 0, stream>>>(
        query, key, value, wqb, wkb, wvb, bq, bk, bv, qh, kh, vt, M, dmodel, dmodel);

    // 3) fused forget-attention
    size_t lds = 16 * 1032 * 2 + 16 * 72 * 2 + 16 * 4;   // 35,392 B -> 4 blocks/CU
    attn_fused<<<dim3(64, 64), 256, lds, stream>>>(qh, kh, vt, gammas, attn_out, ctx);

    // 4) output projection
    gemm_wo<<<dim3(64, 8), 256, 0, stream>>>(ctx, wob, bo, outp, M, dmodel, dmodel);
}